// Round 4
// baseline (767.170 us; speedup 1.0000x reference)
//
#include <hip/hip_runtime.h>
#include <math.h>

// VQ-VAE forward. R16: occupancy re-tiling. conv2 co-split (32-co wave tiles,
// 2048 blocks, 12 waves/CU vs 8); res block 1-row wave tiles (1024 blocks,
// 16 waves/CU vs 8). Accumulation order unchanged -> bit-identical numerics
// to R15. Encoder conv1n, VQ, composed decoder, packs byte-identical.

typedef unsigned short ushort;
typedef short bf16x8 __attribute__((ext_vector_type(8)));
typedef float f32x4 __attribute__((ext_vector_type(4)));

__device__ __forceinline__ ushort f2bf(float f) {
    unsigned u = __builtin_bit_cast(unsigned, f);
    unsigned r = (u + 0x7fffu + ((u >> 16) & 1u)) >> 16;
    return (ushort)r;
}
__device__ __forceinline__ float bfl(unsigned u) { return __builtin_bit_cast(float, u << 16); }
__device__ __forceinline__ float bfh(unsigned u) { return __builtin_bit_cast(float, u & 0xffff0000u); }

__device__ __forceinline__ unsigned relu_u(unsigned u) {
    unsigned m = (u >> 15) & 0x00010001u;
    return u & ~((m << 16) - m);
}
__device__ __forceinline__ uint4 relu4(uint4 v) {
    v.x = relu_u(v.x); v.y = relu_u(v.y); v.z = relu_u(v.z); v.w = relu_u(v.w);
    return v;
}

// ======================= weight packing =======================
// MFMA layout (per layer): [cls][tap][cb(8)][co(256)][k(32)] bf16.

__global__ void k_pack_c3x4(const float* __restrict__ w0, const float* __restrict__ w1,
                            const float* __restrict__ w2, const float* __restrict__ w3,
                            ushort* __restrict__ o0, ushort* __restrict__ o1,
                            ushort* __restrict__ o2, ushort* __restrict__ o3) {
    int layer = blockIdx.x / 2304;
    int i = (blockIdx.x - layer * 2304) * 256 + threadIdx.x;     // 589824
    const float* w = layer == 0 ? w0 : layer == 1 ? w1 : layer == 2 ? w2 : w3;
    ushort* o = layer == 0 ? o0 : layer == 1 ? o1 : layer == 2 ? o2 : o3;
    int kk = i & 31, co = (i >> 5) & 255, cb = (i >> 13) & 7, t = i >> 16;
    int ci = cb * 32 + kk, kh = t / 3, kw = t % 3;
    o[i] = f2bf(w[((co * 256 + ci) * 3 + kh) * 3 + kw]);
}

__global__ void k_pack_c1x1x4(const float* __restrict__ w0, const float* __restrict__ w1,
                              const float* __restrict__ w2, const float* __restrict__ w3,
                              ushort* __restrict__ o0, ushort* __restrict__ o1,
                              ushort* __restrict__ o2, ushort* __restrict__ o3) {
    int layer = blockIdx.x >> 8;
    int i = (blockIdx.x & 255) * 256 + threadIdx.x;              // 65536
    const float* w = layer == 0 ? w0 : layer == 1 ? w1 : layer == 2 ? w2 : w3;
    ushort* o = layer == 0 ? o0 : layer == 1 ? o1 : layer == 2 ? o2 : o3;
    int kk = i & 31, co = (i >> 5) & 255, cb = (i >> 13) & 7;
    o[i] = f2bf(w[co * 256 + cb * 32 + kk]);
}

// conv2 4x4s2 pack: [cls(4 phase)][tap(4)][cb(8)][co(256)][k(32)]
__global__ void k_pack_c2(const float* __restrict__ wc2, ushort* __restrict__ oc2) {
    int i = blockIdx.x * 256 + threadIdx.x;                      // 1048576
    int kk = i & 31, co = (i >> 5) & 255, cb = (i >> 13) & 7;
    int t = (i >> 16) & 3, cls = i >> 18;
    int a = t >> 1, b = t & 1, ci = cb * 32 + kk;
    int ph = cls >> 1, pw = cls & 1;
    int kh = ph ? 2 * a : 2 * a + 1;
    int kw = pw ? 2 * b : 2 * b + 1;
    oc2[i] = f2bf(wc2[((co * 256 + ci) * 4 + kh) * 4 + kw]);
}

__global__ void k_pack_c1f(const float* __restrict__ w, float* __restrict__ o) {
    int i = blockIdx.x * 256 + threadIdx.x;           // 12288
    int co = i & 255, k = i >> 8;
    int ci = k >> 4, kh = (k >> 2) & 3, kw = k & 3;
    o[k * 256 + co] = w[((co * 3 + ci) * 4 + kh) * 4 + kw];
}

__global__ void k_pack_vq(const float* __restrict__ cb, ushort* __restrict__ apk,
                          float* __restrict__ en) {
    if (blockIdx.x < 64) {
        int i = blockIdx.x * 256 + threadIdx.x;
        int j = i & 7, lane = (i >> 3) & 63, s = (i >> 9) & 1, t = i >> 10;
        int code = t * 16 + (lane & 15);
        int dim = s * 32 + (lane >> 4) * 8 + j;
        apk[i] = f2bf(cb[code * 64 + dim]);
    } else {
        int code = threadIdx.x;
        float s = 0.f;
        for (int d = 0; d < 64; ++d) { float v = cb[code * 64 + d]; s += v * v; }
        en[code] = s;
    }
}

// ======================= decoder weight composition =======================
__global__ __launch_bounds__(256) void k_wcomp_dec(const float* __restrict__ dt1,
                                                   const float* __restrict__ dt1b,
                                                   const float* __restrict__ dt2,
                                                   const float* __restrict__ dt2b,
                                                   ushort* __restrict__ wdec,
                                                   float* __restrict__ bdec) {
    __shared__ float s1[4096];     // dt1[ci][m][a][b] slice (16KB)
    __shared__ float s2[12288];    // dt2[m][o][c][d]        (49KB)
    __shared__ float part[2400];
    int ci = blockIdx.x, tid = threadIdx.x;
    for (int i = tid; i < 4096; i += 256) s1[i] = dt1[ci * 4096 + i];
    for (int i = tid; i < 12288; i += 256) s2[i] = dt2[i];
    __syncthreads();

    if (ci == 0 && tid < 48) {     // composed bias per (o, phase)
        int o = tid >> 4, p = tid & 15, py = p >> 2, px = p & 3;
        int c0 = (py + 1) & 1, d0 = (px + 1) & 1;
        float s = dt2b[o];
        for (int m = 0; m < 256; ++m) {
            float t2 = s2[m * 48 + o * 16 + c0 * 4 + d0] + s2[m * 48 + o * 16 + c0 * 4 + d0 + 2]
                     + s2[m * 48 + o * 16 + (c0 + 2) * 4 + d0] + s2[m * 48 + o * 16 + (c0 + 2) * 4 + d0 + 2];
            s += dt1b[m] * t2;
        }
        bdec[tid] = s;
    }

    if (tid < 240) {               // t = y*24 + o*8 + ms
        int y = tid / 24, rem = tid % 24, o = rem / 8, ms = rem % 8;
        int na = 0, aa[2], cc[2];
#pragma unroll
        for (int a = 0; a < 4; ++a) {
            int c = y - 2 * a;
            if ((unsigned)c < 4u) { aa[na] = a; cc[na] = c; ++na; }
        }
        float acc10[10];
#pragma unroll
        for (int xx = 0; xx < 10; ++xx) acc10[xx] = 0.f;
        for (int m = ms * 32; m < ms * 32 + 32; ++m) {
            for (int pa = 0; pa < na; ++pa) {
                float4 d1 = *(const float4*)&s1[m * 16 + aa[pa] * 4];
                float4 d2 = *(const float4*)&s2[m * 48 + o * 16 + cc[pa] * 4];
                acc10[0] += d1.x * d2.x; acc10[1] += d1.x * d2.y; acc10[2] += d1.x * d2.z; acc10[3] += d1.x * d2.w;
                acc10[2] += d1.y * d2.x; acc10[3] += d1.y * d2.y; acc10[4] += d1.y * d2.z; acc10[5] += d1.y * d2.w;
                acc10[4] += d1.z * d2.x; acc10[5] += d1.z * d2.y; acc10[6] += d1.z * d2.z; acc10[7] += d1.z * d2.w;
                acc10[6] += d1.w * d2.x; acc10[7] += d1.w * d2.y; acc10[8] += d1.w * d2.z; acc10[9] += d1.w * d2.w;
            }
        }
#pragma unroll
        for (int xx = 0; xx < 10; ++xx) part[tid * 10 + xx] = acc10[xx];
    }
    __syncthreads();
    if (tid < 300) {
        int y = tid / 30, r = tid % 30, o = r / 10, xx = r % 10;
        float s = 0.f;
#pragma unroll
        for (int ms = 0; ms < 8; ++ms) s += part[((y * 24 + o * 8) + ms) * 10 + xx];
        int du = (y < 3) ? 1 : (y < 7) ? 0 : -1;
        int py = y - 3 + 4 * du;
        int dv = (xx < 3) ? 1 : (xx < 7) ? 0 : -1;
        int px = xx - 3 + 4 * dv;
        int t = (du + 1) * 3 + (dv + 1);
        int cb2 = ci >> 5, kk = ci & 31;
        wdec[((((t * 3 + o) * 8 + cb2) * 16 + py * 4 + px) * 32) + kk] = f2bf(s);
    }
}

// ======================= conv1: 3->256 k4 s2, 128->64, LDS-staged ==============
__global__ __launch_bounds__(256) void k_conv1n(const float* __restrict__ x,
                                                const float* __restrict__ wt,
                                                const float* __restrict__ bias,
                                                ushort* __restrict__ o) {       // NHWC64 bf16
    __shared__ float sx[12][132];
    int b = blockIdx.x;                  // 32n * 64h
    int h = b & 63, n = b >> 6;
    int tid = threadIdx.x;
    for (int c = tid; c < 12 * 128; c += 256) {
        int t = c >> 7, wi = c & 127;
        int ci = t >> 2, kh = t & 3;
        int hi = 2 * h - 1 + kh;
        float v = ((unsigned)hi < 128u) ? x[((long)n * 3 + ci) * 16384 + hi * 128 + wi] : 0.f;
        sx[t][wi + 1] = v;
    }
    if (tid < 24) { int t = tid >> 1; sx[t][(tid & 1) ? 129 : 0] = 0.f; }
    int co = tid;
    float wr[48];
#pragma unroll
    for (int k = 0; k < 48; ++k) wr[k] = wt[k * 256 + co];
    float bco = bias[co];
    __syncthreads();
    ushort* op = o + (((long)n * 64 + h) * 64) * 256 + co;
    for (int w = 0; w < 64; ++w) {
        float acc = bco;
#pragma unroll
        for (int t = 0; t < 12; ++t) {
            const float* xr = &sx[t][2 * w];
            acc += xr[0] * wr[t * 4] + xr[1] * wr[t * 4 + 1]
                 + xr[2] * wr[t * 4 + 2] + xr[3] * wr[t * 4 + 3];
        }
        op[w * 256] = f2bf(acc);
    }
}

// ======================= conv2: 256->256 k4 s2, 64->32 (MFMA) ===================
// Co-split re-tiling of the verified MODE2 mconv: wave tile 32co x 64px
// (2 rows x 32 cols), acc[2][4]. Grid 8mblk x 8coslab x 32n = 2048 blocks of
// 2 waves -> 12 waves/CU (LDS-capped), vs 8 before. Wave-private double-
// buffered staging, barrier-free. Accumulation order identical to R15.
__global__ __launch_bounds__(128, 3) void k_conv2(const ushort* __restrict__ xin,
                                                  const ushort* __restrict__ wpk,
                                                  const float* __restrict__ bias,
                                                  ushort* __restrict__ obf) {
    constexpr int BUFU = 3 * 4 * 34 * 8;             // 3264 ushorts per buffer
    constexpr int WLDS = 2 * BUFU;
    __shared__ __align__(16) ushort sX[2 * WLDS];    // 26112 B (2 waves)

    int tid = threadIdx.x, lane = tid & 63, wv = tid >> 6;
    int q = lane >> 4, l15 = lane & 15;
    int b = blockIdx.x;
    int mblk = b & 7, coslab = (b >> 3) & 7;
    int n = b >> 6;
    int R0 = mblk * 4 + wv * 2;                      // wave's first output row

    ushort* sW = sX + wv * WLDS;

    if (lane < 48) {                                 // zero col pads, both bufs
        int cc = (lane & 1) ? 33 : 0;
        int sq = lane >> 1;                          // 0..23 spans both bufs
        uint4 z; z.x = z.y = z.z = z.w = 0;
        *(uint4*)&sW[(sq * 34 + cc) * 8] = z;
    }

    int brr[4], bcol[4];
#pragma unroll
    for (int bt = 0; bt < 4; ++bt) {
        int p = bt * 16 + l15;
        brr[bt] = p >> 5; bcol[bt] = (p & 31) + 1;
    }

    int scol = lane >> 1, j0 = (lane & 1) * 2;
    int aoff = (coslab * 32 + l15) * 32 + q * 8;

    f32x4 acc[2][4];
#pragma unroll
    for (int at = 0; at < 2; ++at)
#pragma unroll
        for (int bt = 0; bt < 4; ++bt) acc[at][bt] = 0.f;

    uint4 sreg[3][2];
    auto stage_load = [&](int it2) {
        int cb2 = it2 >> 2, ph2 = it2 & 3;
        int ph_h2 = ph2 >> 1, ph_w2 = ph2 & 1;
        int hh0 = R0 - ph_h2;
#pragma unroll
        for (int r = 0; r < 3; ++r) {
            int hh = hh0 + r;
            bool valid = (unsigned)hh < 32u;
            long off = (((long)n * 64 + 2 * hh + ph_h2) * 64 + (2 * scol + ph_w2)) * 256 + cb2 * 32 + j0 * 8;
#pragma unroll
            for (int k = 0; k < 2; ++k) {
                uint4 v;
                if (valid) v = *(const uint4*)(xin + off + k * 8);
                else { v.x = 0; v.y = 0; v.z = 0; v.w = 0; }
                sreg[r][k] = v;
            }
        }
    };
    auto write_stage = [&](int pbuf) {
        ushort* bufp = sW + pbuf * BUFU;
#pragma unroll
        for (int r = 0; r < 3; ++r)
#pragma unroll
            for (int k = 0; k < 2; ++k)
                *(uint4*)&bufp[((r * 4 + j0 + k) * 34 + scol + 1) * 8] = sreg[r][k];
    };

    stage_load(0);
    write_stage(0);

    for (int it = 0; it < 32; ++it) {
        int cb = it >> 2, ph = it & 3;
        int ph_w = ph & 1;
        const ushort* wb = wpk + ((long)(ph * 4) * 8 + cb) * 8192 + aoff;
        ushort* bufp = sW + (it & 1) * BUFU;

        if (it + 1 < 32) stage_load(it + 1);         // loads in flight during MFMA

        bf16x8 afA[4][2];
#pragma unroll
        for (int t = 0; t < 4; ++t)
#pragma unroll
            for (int at = 0; at < 2; ++at)
                afA[t][at] = *(const bf16x8*)(wb + (long)t * 65536 + at * 512);
#pragma unroll
        for (int t = 0; t < 4; ++t) {
            int taprow = t >> 1, dx = (t & 1) - ph_w;
            bf16x8 bfr[4];
#pragma unroll
            for (int bt = 0; bt < 4; ++bt)
                bfr[bt] = *(const bf16x8*)&bufp[(((brr[bt] + taprow) * 4 + q) * 34 + bcol[bt] + dx) * 8];
#pragma unroll
            for (int at = 0; at < 2; ++at)
#pragma unroll
                for (int bt = 0; bt < 4; ++bt)
                    acc[at][bt] = __builtin_amdgcn_mfma_f32_16x16x32_bf16(afA[t][at], bfr[bt],
                                                                          acc[at][bt], 0, 0, 0);
        }

        if (it + 1 < 32) write_stage((it + 1) & 1);
    }

    int co_base = coslab * 32;
#pragma unroll
    for (int at = 0; at < 2; ++at) {
        int co_t = co_base + at * 16 + q * 4;
        float4 b4 = *(const float4*)(bias + co_t);
        float bv[4] = {b4.x, b4.y, b4.z, b4.w};
#pragma unroll
        for (int bt = 0; bt < 4; ++bt) {
            int m = R0 * 32 + bt * 16 + l15;
            long oaddr = ((long)n * 1024 + m) * 256 + co_t;
            float v[4];
#pragma unroll
            for (int r = 0; r < 4; ++r) v[r] = acc[at][bt][r] + bv[r];
            uint2 pk;
            pk.x = (unsigned)f2bf(v[0]) | ((unsigned)f2bf(v[1]) << 16);
            pk.y = (unsigned)f2bf(v[2]) | ((unsigned)f2bf(v[3]) << 16);
            *(uint2*)(obf + oaddr) = pk;
        }
    }
}

// ======================= fused res block (1-row tiles) =======================
// out = x + conv1x1(relu(conv3x3(relu(x)))). Block: 256 thr = 4 waves, each
// wave owns co slab wv*64, all share ONE output row R of 32 px. Cooperative
// double-buffered 3-row staging (wave w<3 stages window row w; one barrier per
// cb iteration — R15-verified pattern). 3x3 relu'd bf16 output to 16KB LDS
// exchange ex[px 32][ci 256] with octet XOR swizzle ci^((px&7)<<3) (involution
// on write+read). Grid 32rows x 32n = 1024 blocks -> 16 waves/CU.
__global__ __launch_bounds__(256, 4) void k_resblock(const ushort* __restrict__ xin,
                                                     const ushort* __restrict__ w3pk,
                                                     const ushort* __restrict__ w1pk,
                                                     ushort* __restrict__ obf) {
    constexpr int BUFU = 3 * 4 * 34 * 8;             // 3264 ushorts per buffer
    __shared__ __align__(16) ushort sX[2 * BUFU];    // 13056 B staging
    __shared__ __align__(16) ushort sEx[32 * 256];   // 16384 B exchange

    int tid = threadIdx.x, lane = tid & 63, wv = tid >> 6;
    int q = lane >> 4, l15 = lane & 15;
    int b = blockIdx.x;                              // 32 rows * 32 n
    int R = b & 31, n = b >> 5;

    if (tid < 48) {                                  // zero col pads, both bufs
        int cc = (tid & 1) ? 33 : 0;
        int sq = tid >> 1;                           // 0..23 spans both bufs
        uint4 z; z.x = z.y = z.z = z.w = 0;
        *(uint4*)&sX[(sq * 34 + cc) * 8] = z;
    }

    int scol = lane >> 1, j0 = (lane & 1) * 2;
    int aoff = (wv * 64 + l15) * 32 + q * 8;

    f32x4 acc[4][2];
#pragma unroll
    for (int at = 0; at < 4; ++at)
#pragma unroll
        for (int bt = 0; bt < 2; ++bt) acc[at][bt] = 0.f;

    // cooperative staging: wave w<3 stages window row w (input row R-1+w)
    int hh = R - 1 + wv;
    bool hval = (wv < 3) && ((unsigned)hh < 32u);
    uint4 sreg[2];
    auto stage_load = [&](int cb2) {
        long off = (((long)n * 32 + hh) * 32 + scol) * 256 + cb2 * 32 + j0 * 8;
#pragma unroll
        for (int k = 0; k < 2; ++k) {
            uint4 v;
            if (hval) v = relu4(*(const uint4*)(xin + off + k * 8));
            else { v.x = 0; v.y = 0; v.z = 0; v.w = 0; }
            sreg[k] = v;
        }
    };
    auto write_stage = [&](int pbuf) {
        if (wv < 3) {
            ushort* bufp = sX + pbuf * BUFU;
#pragma unroll
            for (int k = 0; k < 2; ++k)
                *(uint4*)&bufp[((wv * 4 + j0 + k) * 34 + scol + 1) * 8] = sreg[k];
        }
    };

    stage_load(0);
    write_stage(0);
    __syncthreads();                                 // pads + buf0 visible

    // ---- 3x3 over 8 ci-octet slabs ----
    for (int cb = 0; cb < 8; ++cb) {
        ushort* bufp = sX + (cb & 1) * BUFU;
        if (cb + 1 < 8) stage_load(cb + 1);
        const ushort* wb = w3pk + (long)cb * 8192 + aoff;

        bf16x8 afc[4];
#pragma unroll
        for (int at = 0; at < 4; ++at) afc[at] = *(const bf16x8*)(wb + at * 512);
#pragma unroll
        for (int t = 0; t < 9; ++t) {
            bf16x8 afn[4];
            if (t < 8) {
#pragma unroll
                for (int at = 0; at < 4; ++at)
                    afn[at] = *(const bf16x8*)(wb + (long)(t + 1) * 65536 + at * 512);
            }
            int taprow = t / 3, dx = t % 3 - 1;
            bf16x8 bfr[2];
#pragma unroll
            for (int bt = 0; bt < 2; ++bt)
                bfr[bt] = *(const bf16x8*)&bufp[((taprow * 4 + q) * 34 + bt * 16 + l15 + 1 + dx) * 8];
#pragma unroll
            for (int at = 0; at < 4; ++at)
#pragma unroll
                for (int bt = 0; bt < 2; ++bt)
                    acc[at][bt] = __builtin_amdgcn_mfma_f32_16x16x32_bf16(afc[at], bfr[bt],
                                                                          acc[at][bt], 0, 0, 0);
            if (t < 8) {
#pragma unroll
                for (int at = 0; at < 4; ++at) afc[at] = afn[at];
            }
        }

        if (cb + 1 < 8) {
            write_stage((cb + 1) & 1);
            __syncthreads();
        }
    }

    // ---- 3x3 epilogue: relu -> bf16 -> exchange LDS ----
#pragma unroll
    for (int at = 0; at < 4; ++at) {
        int co_t = wv * 64 + at * 16 + q * 4;
#pragma unroll
        for (int bt = 0; bt < 2; ++bt) {
            int px = bt * 16 + l15;
            uint2 pk;
            pk.x = (unsigned)f2bf(fmaxf(acc[at][bt][0], 0.f))
                 | ((unsigned)f2bf(fmaxf(acc[at][bt][1], 0.f)) << 16);
            pk.y = (unsigned)f2bf(fmaxf(acc[at][bt][2], 0.f))
                 | ((unsigned)f2bf(fmaxf(acc[at][bt][3], 0.f)) << 16);
            *(uint2*)&sEx[px * 256 + (co_t ^ ((px & 7) << 3))] = pk;
        }
    }
    __syncthreads();

    // ---- 1x1 over 8 ci-octet slabs from exchange ----
    f32x4 acc2[4][2];
#pragma unroll
    for (int at = 0; at < 4; ++at)
#pragma unroll
        for (int bt = 0; bt < 2; ++bt) acc2[at][bt] = 0.f;

    for (int cb = 0; cb < 8; ++cb) {
        const ushort* wb1 = w1pk + (long)cb * 8192 + aoff;
        bf16x8 af1[4];
#pragma unroll
        for (int at = 0; at < 4; ++at) af1[at] = *(const bf16x8*)(wb1 + at * 512);
        bf16x8 bf1[2];
#pragma unroll
        for (int bt = 0; bt < 2; ++bt) {
            int px = bt * 16 + l15;
            bf1[bt] = *(const bf16x8*)&sEx[px * 256 + ((cb * 32 + q * 8) ^ ((px & 7) << 3))];
        }
#pragma unroll
        for (int at = 0; at < 4; ++at)
#pragma unroll
            for (int bt = 0; bt < 2; ++bt)
                acc2[at][bt] = __builtin_amdgcn_mfma_f32_16x16x32_bf16(af1[at], bf1[bt],
                                                                      acc2[at][bt], 0, 0, 0);
    }

    // ---- final epilogue: + residual (raw input), bf16 store ----
#pragma unroll
    for (int at = 0; at < 4; ++at) {
        int co_t = wv * 64 + at * 16 + q * 4;
#pragma unroll
        for (int bt = 0; bt < 2; ++bt) {
            int m = R * 32 + bt * 16 + l15;
            long oaddr = ((long)n * 1024 + m) * 256 + co_t;
            uint2 rr = *(const uint2*)(xin + oaddr);
            float v[4];
            v[0] = acc2[at][bt][0] + bfl(rr.x);
            v[1] = acc2[at][bt][1] + bfh(rr.x);
            v[2] = acc2[at][bt][2] + bfl(rr.y);
            v[3] = acc2[at][bt][3] + bfh(rr.y);
            uint2 pk;
            pk.x = (unsigned)f2bf(v[0]) | ((unsigned)f2bf(v[1]) << 16);
            pk.y = (unsigned)f2bf(v[2]) | ((unsigned)f2bf(v[3]) << 16);
            *(uint2*)(obf + oaddr) = pk;
        }
    }
}

// ======================= VQ via MFMA (bf16 out) =======================
__global__ __launch_bounds__(256) void k_vq2(const ushort* __restrict__ zb,
                                             const ushort* __restrict__ apk,
                                             const float* __restrict__ en,
                                             const float* __restrict__ cbf,
                                             ushort* __restrict__ vqb,
                                             float* __restrict__ loss) {
    __shared__ int sIdx[64];
    __shared__ float sLoss[64];
    int tid = threadIdx.x, lane = tid & 63, wv = tid >> 6;
    int q = lane >> 4, l15 = lane & 15;
    int r0 = blockIdx.x * 64;
    int R = r0 + wv * 16;

    const ushort* zp = zb + ((long)(R + l15)) * 64 + q * 8;
    bf16x8 b0 = *(const bf16x8*)zp;
    bf16x8 b1 = *(const bf16x8*)(zp + 32);

    float z2 = 0.f;
    {
        const unsigned* u0 = (const unsigned*)&b0;
        const unsigned* u1 = (const unsigned*)&b1;
#pragma unroll
        for (int i = 0; i < 4; ++i) {
            float a = bfl(u0[i]), bb = bfh(u0[i]);
            float c = bfl(u1[i]), d = bfh(u1[i]);
            z2 += a * a + bb * bb + c * c + d * d;
        }
    }

    float best = 3.4e38f;
    int bidx = 0;
#pragma unroll
    for (int t = 0; t < 16; ++t) {
        bf16x8 a0 = *(const bf16x8*)(apk + ((t * 2 + 0) * 64 + lane) * 8);
        bf16x8 a1 = *(const bf16x8*)(apk + ((t * 2 + 1) * 64 + lane) * 8);
        f32x4 acc = {0.f, 0.f, 0.f, 0.f};
        acc = __builtin_amdgcn_mfma_f32_16x16x32_bf16(a0, b0, acc, 0, 0, 0);
        acc = __builtin_amdgcn_mfma_f32_16x16x32_bf16(a1, b1, acc, 0, 0, 0);
        float4 e4 = *(const float4*)(en + t * 16 + q * 4);
        float sc[4] = {e4.x - 2.f * acc[0], e4.y - 2.f * acc[1],
                       e4.z - 2.f * acc[2], e4.w - 2.f * acc[3]};
#pragma unroll
        for (int r = 0; r < 4; ++r) {
            int code = t * 16 + q * 4 + r;
            if (sc[r] < best) { best = sc[r]; bidx = code; }
        }
    }
#pragma unroll
    for (int m = 16; m <= 32; m <<= 1) {
        float ob = __shfl_xor(best, m);
        int oi = __shfl_xor(bidx, m);
        if (ob < best || (ob == best && oi < bidx)) { best = ob; bidx = oi; }
        z2 += __shfl_xor(z2, m);
    }
    if (q == 0) {
        sIdx[wv * 16 + l15] = bidx;
        sLoss[wv * 16 + l15] = best + z2;
    }
    __syncthreads();

    if (wv == 0) {
        float l = sLoss[lane];
#pragma unroll
        for (int m = 1; m < 64; m <<= 1) l += __shfl_xor(l, m);
        if (lane == 0) atomicAdd(loss, l * (1.25f / 8388608.f));
    }

    unsigned* vb = (unsigned*)(vqb + (long)r0 * 64);
#pragma unroll
    for (int k = 0; k < 8; ++k) {
        int i = k * 256 + tid;
        int rl = i >> 5, jp = i & 31;
        int idx = sIdx[rl];
        float v0 = cbf[idx * 64 + 2 * jp];
        float v1 = cbf[idx * 64 + 2 * jp + 1];
        vb[i] = (unsigned)f2bf(v0) | ((unsigned)f2bf(v1) << 16);
    }
}

// ======================= composed decoder deconv: 256->3 k10 s4, 32->128 ========
__global__ __launch_bounds__(128, 2) void k_dec_comp(const ushort* __restrict__ xin,
                                                     const ushort* __restrict__ wdec,
                                                     const float* __restrict__ bdec,
                                                     float* __restrict__ out) {
    constexpr int BUFU = 3 * 4 * 34 * 8;             // 3264 ushorts
    constexpr int WLDS = 2 * BUFU;
    __shared__ __align__(16) ushort sX[2 * WLDS];    // 26112 B

    int tid = threadIdx.x, lane = tid & 63, wv = tid >> 6;
    int q = lane >> 4, l15 = lane & 15;
    int b = blockIdx.x;                              // 32n * 16rp
    int rp = b & 15, n = b >> 4;
    int U = rp * 2 + wv;
    ushort* sW = sX + wv * WLDS;

    if (lane < 48) {
        int cc = (lane & 1) ? 33 : 0;
        int sq = lane >> 1;
        uint4 z; z.x = z.y = z.z = z.w = 0;
        *(uint4*)&sW[(sq * 34 + cc) * 8] = z;
    }
    int scol = lane >> 1, j0 = (lane & 1) * 2;

    f32x4 acc[3][2];
#pragma unroll
    for (int o = 0; o < 3; ++o)
#pragma unroll
        for (int bt = 0; bt < 2; ++bt) acc[o][bt] = 0.f;

    uint4 sreg[3][2];
    auto stage_load = [&](int cb2) {
#pragma unroll
        for (int r = 0; r < 3; ++r) {
            int hh = U - 1 + r;
            bool valid = (unsigned)hh < 32u;
            long off = (((long)n * 32 + hh) * 32 + scol) * 256 + cb2 * 32 + j0 * 8;
#pragma unroll
            for (int k = 0; k < 2; ++k) {
                uint4 v;
                if (valid) v = *(const uint4*)(xin + off + k * 8);
                else { v.x = 0; v.y = 0; v.z = 0; v.w = 0; }
                sreg[r][k] = v;
            }
        }
    };
    auto write_stage = [&](int pbuf) {
        ushort* bufp = sW + pbuf * BUFU;
#pragma unroll
        for (int r = 0; r < 3; ++r)
#pragma unroll
            for (int k = 0; k < 2; ++k)
                *(uint4*)&bufp[((r * 4 + j0 + k) * 34 + scol + 1) * 8] = sreg[r][k];
    };

    stage_load(0);
    write_stage(0);

    for (int cb = 0; cb < 8; ++cb) {
        ushort* bufp = sW + (cb & 1) * BUFU;
        if (cb + 1 < 8) stage_load(cb + 1);
        const ushort* wb = wdec + (long)cb * 512 + l15 * 32 + q * 8;
#pragma unroll
        for (int t = 0; t < 9; ++t) {
            int du = t / 3 - 1, dv = t % 3 - 1;
            bf16x8 bfr[2];
#pragma unroll
            for (int bt = 0; bt < 2; ++bt)
                bfr[bt] = *(const bf16x8*)&bufp[(((du + 1) * 4 + q) * 34 + bt * 16 + l15 + 1 + dv) * 8];
#pragma unroll
            for (int o = 0; o < 3; ++o) {
                bf16x8 af = *(const bf16x8*)(wb + (long)(t * 3 + o) * 4096);
#pragma unroll
                for (int bt = 0; bt < 2; ++bt)
                    acc[o][bt] = __builtin_amdgcn_mfma_f32_16x16x32_bf16(af, bfr[bt], acc[o][bt], 0, 0, 0);
            }
        }
        if (cb + 1 < 8) write_stage((cb + 1) & 1);
    }

#pragma unroll
    for (int o = 0; o < 3; ++o) {
#pragma unroll
        for (int bt = 0; bt < 2; ++bt) {
            int V = bt * 16 + l15;
#pragma unroll
            for (int r = 0; r < 4; ++r) {
                int p = q * 4 + r, py = p >> 2, px = p & 3;
                out[(((long)n * 3 + o) * 128 + 4 * U + py) * 128 + 4 * V + px] =
                    tanhf(acc[o][bt][r] + bdec[o * 16 + p]);
            }
        }
    }
}

// ======================= launcher =======================
extern "C" void kernel_launch(void* const* d_in, const int* in_sizes, int n_in,
                              void* d_out, int out_size, void* d_ws, size_t ws_size,
                              hipStream_t stream) {
    (void)in_sizes; (void)n_in; (void)out_size; (void)ws_size;
    const float* x        = (const float*)d_in[0];
    const float* enc_w1   = (const float*)d_in[1];
    const float* enc_b1   = (const float*)d_in[2];
    const float* enc_w2   = (const float*)d_in[3];
    const float* enc_b2   = (const float*)d_in[4];
    const float* er1_w3   = (const float*)d_in[5];
    const float* er1_w1   = (const float*)d_in[6];
    const float* er2_w3   = (const float*)d_in[7];
    const float* er2_w1   = (const float*)d_in[8];
    const float* codebook = (const float*)d_in[9];
    const float* dr1_w3   = (const float*)d_in[10];
    const float* dr1_w1   = (const float*)d_in[11];
    const float* dr2_w3   = (const float*)d_in[12];
    const float* dr2_w1   = (const float*)d_in[13];
    const float* dt1_w    = (const float*)d_in[14];
    const float* dt1_b    = (const float*)d_in[15];
    const float* dt2_w    = (const float*)d_in[16];
    const float* dt2_b    = (const float*)d_in[17];

    float* recon = (float*)d_out;
    float* loss  = recon + 1572864;

    char* ws = (char*)d_ws;
    size_t off = 0;
    auto alloc = [&](size_t bytes) { char* p = ws + off; off += (bytes + 255) & ~(size_t)255; return p; };
    ushort* N64  = (ushort*)alloc(67108864);   // [32,64,64,256] bf16
    ushort* X0   = (ushort*)alloc(16777216);   // bf16 NHWC 32x32 tensors
    ushort* X2   = (ushort*)alloc(16777216);
    ushort* X3   = (ushort*)alloc(16777216);
    ushort* X4   = (ushort*)alloc(16777216);
    ushort* wpk_c2   = (ushort*)alloc(2097152);
    ushort* wpk_er13 = (ushort*)alloc(1179648);
    ushort* wpk_er23 = (ushort*)alloc(1179648);
    ushort* wpk_dr13 = (ushort*)alloc(1179648);
    ushort* wpk_dr23 = (ushort*)alloc(1179648);
    ushort* wpk_er11 = (ushort*)alloc(131072);
    ushort* wpk_er21 = (ushort*)alloc(131072);
    ushort* wpk_dr11 = (ushort*)alloc(131072);
    ushort* wpk_dr21 = (ushort*)alloc(131072);
    float*  wt_c1    = (float*)alloc(49152);
    ushort* wdec     = (ushort*)alloc(221184); // [9][3][8][16][32] bf16
    ushort* apk      = (ushort*)alloc(32768);
    float*  bdec     = (float*)alloc(192);
    float*  en       = (float*)alloc(1024);

    hipMemsetAsync(loss, 0, sizeof(float), stream);
    hipMemsetAsync(wdec, 0, 221184, stream);

    // weight packing
    k_pack_c1f<<<48, 256, 0, stream>>>(enc_w1, wt_c1);
    k_pack_c2<<<4096, 256, 0, stream>>>(enc_w2, wpk_c2);
    k_pack_c3x4<<<9216, 256, 0, stream>>>(er1_w3, er2_w3, dr1_w3, dr2_w3,
                                          wpk_er13, wpk_er23, wpk_dr13, wpk_dr23);
    k_pack_c1x1x4<<<1024, 256, 0, stream>>>(er1_w1, er2_w1, dr1_w1, dr2_w1,
                                            wpk_er11, wpk_er21, wpk_dr11, wpk_dr21);
    k_pack_vq<<<65, 256, 0, stream>>>(codebook, apk, en);
    k_wcomp_dec<<<256, 256, 0, stream>>>(dt1_w, dt1_b, dt2_w, dt2_b, wdec, bdec);

    // encoder (verified two-stage)
    k_conv1n<<<2048, 256, 0, stream>>>(x, wt_c1, enc_b1, N64);
    k_conv2<<<2048, 128, 0, stream>>>(N64, wpk_c2, enc_b2, X0);
    // fused res blocks (encoder)
    k_resblock<<<1024, 256, 0, stream>>>(X0, wpk_er13, wpk_er11, X2);
    k_resblock<<<1024, 256, 0, stream>>>(X2, wpk_er23, wpk_er21, X3);
    // VQ: X3 -> X4 (vq, no relu) + loss
    k_vq2<<<2048, 256, 0, stream>>>(X3, apk, en, codebook, X4, loss);
    // fused res blocks (decoder)
    k_resblock<<<1024, 256, 0, stream>>>(X4, wpk_dr13, wpk_dr11, X0);
    k_resblock<<<1024, 256, 0, stream>>>(X0, wpk_dr23, wpk_dr21, X2);
    // decoder (composed deconv1∘deconv2 + tanh): X2 -> recon
    k_dec_comp<<<512, 128, 0, stream>>>(X2, wdec, bdec, recon);
}

// Round 5
// 670.395 us; speedup vs baseline: 1.1444x; 1.1444x over previous
//
#include <hip/hip_runtime.h>
#include <math.h>

// VQ-VAE forward. R17: composed encoder (conv1∘conv2 = k10s4) REINSTATED with
// the R13 bug fixed: wcomp writer tails used tid<300/320 with 256-thread
// blocks -> wenc y>=8 slabs never written (garbage/zero) -> the 0.469 loss
// error. Both wcomp kernels now grid-stride their tails (also fixes latent
// missing-tap bug in the passing composed decoder). Exact border correction
// for conv2's z1 zero-padding vs virtual-row composition (k_wcorr +
// k_fix_border). conv2/resblock tilings reverted to R15 (R16's occupancy
// re-tiling regressed: staging overhead per MFMA doubled).

typedef unsigned short ushort;
typedef short bf16x8 __attribute__((ext_vector_type(8)));
typedef float f32x4 __attribute__((ext_vector_type(4)));

__device__ __forceinline__ ushort f2bf(float f) {
    unsigned u = __builtin_bit_cast(unsigned, f);
    unsigned r = (u + 0x7fffu + ((u >> 16) & 1u)) >> 16;
    return (ushort)r;
}
__device__ __forceinline__ float bfl(unsigned u) { return __builtin_bit_cast(float, u << 16); }
__device__ __forceinline__ float bfh(unsigned u) { return __builtin_bit_cast(float, u & 0xffff0000u); }

__device__ __forceinline__ unsigned relu_u(unsigned u) {
    unsigned m = (u >> 15) & 0x00010001u;
    return u & ~((m << 16) - m);
}
__device__ __forceinline__ uint4 relu4(uint4 v) {
    v.x = relu_u(v.x); v.y = relu_u(v.y); v.z = relu_u(v.z); v.w = relu_u(v.w);
    return v;
}

// ======================= weight packing (res blocks, VQ) =======================
__global__ void k_pack_c3x4(const float* __restrict__ w0, const float* __restrict__ w1,
                            const float* __restrict__ w2, const float* __restrict__ w3,
                            ushort* __restrict__ o0, ushort* __restrict__ o1,
                            ushort* __restrict__ o2, ushort* __restrict__ o3) {
    int layer = blockIdx.x / 2304;
    int i = (blockIdx.x - layer * 2304) * 256 + threadIdx.x;     // 589824
    const float* w = layer == 0 ? w0 : layer == 1 ? w1 : layer == 2 ? w2 : w3;
    ushort* o = layer == 0 ? o0 : layer == 1 ? o1 : layer == 2 ? o2 : o3;
    int kk = i & 31, co = (i >> 5) & 255, cb = (i >> 13) & 7, t = i >> 16;
    int ci = cb * 32 + kk, kh = t / 3, kw = t % 3;
    o[i] = f2bf(w[((co * 256 + ci) * 3 + kh) * 3 + kw]);
}

__global__ void k_pack_c1x1x4(const float* __restrict__ w0, const float* __restrict__ w1,
                              const float* __restrict__ w2, const float* __restrict__ w3,
                              ushort* __restrict__ o0, ushort* __restrict__ o1,
                              ushort* __restrict__ o2, ushort* __restrict__ o3) {
    int layer = blockIdx.x >> 8;
    int i = (blockIdx.x & 255) * 256 + threadIdx.x;              // 65536
    const float* w = layer == 0 ? w0 : layer == 1 ? w1 : layer == 2 ? w2 : w3;
    ushort* o = layer == 0 ? o0 : layer == 1 ? o1 : layer == 2 ? o2 : o3;
    int kk = i & 31, co = (i >> 5) & 255, cb = (i >> 13) & 7;
    o[i] = f2bf(w[co * 256 + cb * 32 + kk]);
}

__global__ void k_pack_vq(const float* __restrict__ cb, ushort* __restrict__ apk,
                          float* __restrict__ en) {
    if (blockIdx.x < 64) {
        int i = blockIdx.x * 256 + threadIdx.x;
        int j = i & 7, lane = (i >> 3) & 63, s = (i >> 9) & 1, t = i >> 10;
        int code = t * 16 + (lane & 15);
        int dim = s * 32 + (lane >> 4) * 8 + j;
        apk[i] = f2bf(cb[code * 64 + dim]);
    } else {
        int code = threadIdx.x;
        float s = 0.f;
        for (int d = 0; d < 64; ++d) { float v = cb[code * 64 + d]; s += v * v; }
        en[code] = s;
    }
}

// ======================= encoder weight composition =======================
// W_eff[co,ci,y,x] = sum_{2k2h+k1h=y} sum_{2k2w+k1w=x} sum_m w2[co,m,k2h,k2w]*w1[m,ci,k1h,k1w]
// packed wenc[y(10)][co(256)][k(32)], k = xx*3+ci (30 used, 2 zeroed).
__global__ __launch_bounds__(256) void k_wcomp_enc(const float* __restrict__ w1,
                                                   const float* __restrict__ b1f,
                                                   const float* __restrict__ w2,
                                                   const float* __restrict__ b2f,
                                                   ushort* __restrict__ wenc,
                                                   float* __restrict__ benc) {
    __shared__ float sw1[12288];   // w1[m][ci][k1h][k1w]
    __shared__ float sw2[4096];    // w2[co][m][k2h][k2w]
    __shared__ float part[2400];
    int co = blockIdx.x, tid = threadIdx.x;
    for (int i = tid; i < 12288; i += 256) sw1[i] = w1[i];
    for (int i = tid; i < 4096; i += 256) sw2[i] = w2[co * 4096 + i];
    __syncthreads();

    {   // bias (exact since b1=0; interior formula)
        float s = 0.f;
#pragma unroll
        for (int t = 0; t < 16; ++t) s += sw2[tid * 16 + t];
        float pb = b1f[tid] * s;
#pragma unroll
        for (int m = 1; m < 64; m <<= 1) pb += __shfl_xor(pb, m);
        if ((tid & 63) == 0) part[tid >> 6] = pb;
    }
    __syncthreads();
    if (tid == 0) benc[co] = b2f[co] + part[0] + part[1] + part[2] + part[3];

    if (tid < 240) {               // t = y*24 + ci*8 + ms
        int y = tid / 24, rem = tid % 24, ci = rem / 8, ms = rem % 8;
        int na = 0, aa[2], h1[2];
#pragma unroll
        for (int a = 0; a < 4; ++a) {
            int k1 = y - 2 * a;
            if ((unsigned)k1 < 4u) { aa[na] = a; h1[na] = k1; ++na; }
        }
        float acc10[10];
#pragma unroll
        for (int xx = 0; xx < 10; ++xx) acc10[xx] = 0.f;
        for (int m = ms * 32; m < ms * 32 + 32; ++m) {
            for (int pa = 0; pa < na; ++pa) {
                float4 a2 = *(const float4*)&sw2[m * 16 + aa[pa] * 4];
                float4 a1 = *(const float4*)&sw1[m * 48 + ci * 16 + h1[pa] * 4];
                // acc10[2*k2w + k1w] += a2[k2w] * a1[k1w]
                acc10[0] += a2.x * a1.x; acc10[1] += a2.x * a1.y; acc10[2] += a2.x * a1.z; acc10[3] += a2.x * a1.w;
                acc10[2] += a2.y * a1.x; acc10[3] += a2.y * a1.y; acc10[4] += a2.y * a1.z; acc10[5] += a2.y * a1.w;
                acc10[4] += a2.z * a1.x; acc10[5] += a2.z * a1.y; acc10[6] += a2.z * a1.z; acc10[7] += a2.z * a1.w;
                acc10[6] += a2.w * a1.x; acc10[7] += a2.w * a1.y; acc10[8] += a2.w * a1.z; acc10[9] += a2.w * a1.w;
            }
        }
#pragma unroll
        for (int xx = 0; xx < 10; ++xx) part[tid * 10 + xx] = acc10[xx];
    }
    __syncthreads();
    // FIXED (R13 bug): grid-stride to cover all 320 writer slots with 256 thr.
    for (int w = tid; w < 320; w += 256) {
        if (w < 300) {
            int y = w / 30, r = w % 30, ci = r / 10, xx = r % 10;
            float s = 0.f;
#pragma unroll
            for (int ms = 0; ms < 8; ++ms) s += part[((y * 24 + ci * 8) + ms) * 10 + xx];
            wenc[(y * 256 + co) * 32 + xx * 3 + ci] = f2bf(s);
        } else {
            int j = w - 300;
            int y = j >> 1;
            wenc[(y * 256 + co) * 32 + 30 + (j & 1)] = 0;
        }
    }
}

// ======================= decoder weight composition =======================
__global__ __launch_bounds__(256) void k_wcomp_dec(const float* __restrict__ dt1,
                                                   const float* __restrict__ dt1b,
                                                   const float* __restrict__ dt2,
                                                   const float* __restrict__ dt2b,
                                                   ushort* __restrict__ wdec,
                                                   float* __restrict__ bdec) {
    __shared__ float s1[4096];
    __shared__ float s2[12288];
    __shared__ float part[2400];
    int ci = blockIdx.x, tid = threadIdx.x;
    for (int i = tid; i < 4096; i += 256) s1[i] = dt1[ci * 4096 + i];
    for (int i = tid; i < 12288; i += 256) s2[i] = dt2[i];
    __syncthreads();

    if (ci == 0 && tid < 48) {
        int o = tid >> 4, p = tid & 15, py = p >> 2, px = p & 3;
        int c0 = (py + 1) & 1, d0 = (px + 1) & 1;
        float s = dt2b[o];
        for (int m = 0; m < 256; ++m) {
            float t2 = s2[m * 48 + o * 16 + c0 * 4 + d0] + s2[m * 48 + o * 16 + c0 * 4 + d0 + 2]
                     + s2[m * 48 + o * 16 + (c0 + 2) * 4 + d0] + s2[m * 48 + o * 16 + (c0 + 2) * 4 + d0 + 2];
            s += dt1b[m] * t2;
        }
        bdec[tid] = s;
    }

    if (tid < 240) {
        int y = tid / 24, rem = tid % 24, o = rem / 8, ms = rem % 8;
        int na = 0, aa[2], cc[2];
#pragma unroll
        for (int a = 0; a < 4; ++a) {
            int c = y - 2 * a;
            if ((unsigned)c < 4u) { aa[na] = a; cc[na] = c; ++na; }
        }
        float acc10[10];
#pragma unroll
        for (int xx = 0; xx < 10; ++xx) acc10[xx] = 0.f;
        for (int m = ms * 32; m < ms * 32 + 32; ++m) {
            for (int pa = 0; pa < na; ++pa) {
                float4 d1 = *(const float4*)&s1[m * 16 + aa[pa] * 4];
                float4 d2 = *(const float4*)&s2[m * 48 + o * 16 + cc[pa] * 4];
                acc10[0] += d1.x * d2.x; acc10[1] += d1.x * d2.y; acc10[2] += d1.x * d2.z; acc10[3] += d1.x * d2.w;
                acc10[2] += d1.y * d2.x; acc10[3] += d1.y * d2.y; acc10[4] += d1.y * d2.z; acc10[5] += d1.y * d2.w;
                acc10[4] += d1.z * d2.x; acc10[5] += d1.z * d2.y; acc10[6] += d1.z * d2.z; acc10[7] += d1.z * d2.w;
                acc10[6] += d1.w * d2.x; acc10[7] += d1.w * d2.y; acc10[8] += d1.w * d2.z; acc10[9] += d1.w * d2.w;
            }
        }
#pragma unroll
        for (int xx = 0; xx < 10; ++xx) part[tid * 10 + xx] = acc10[xx];
    }
    __syncthreads();
    // FIXED (same tid<300 bug, previously masked by memset wdec): grid-stride.
    for (int w = tid; w < 300; w += 256) {
        int y = w / 30, r = w % 30, o = r / 10, xx = r % 10;
        float s = 0.f;
#pragma unroll
        for (int ms = 0; ms < 8; ++ms) s += part[((y * 24 + o * 8) + ms) * 10 + xx];
        int du = (y < 3) ? 1 : (y < 7) ? 0 : -1;
        int py = y - 3 + 4 * du;
        int dv = (xx < 3) ? 1 : (xx < 7) ? 0 : -1;
        int px = xx - 3 + 4 * dv;
        int t = (du + 1) * 3 + (dv + 1);
        int cb2 = ci >> 5, kk = ci & 31;
        wdec[((((t * 3 + o) * 8 + cb2) * 16 + py * 4 + px) * 32) + kk] = f2bf(s);
    }
}

// ======================= border-correction weights =======================
// Composed encoder implicitly uses "virtual" z1 rows/cols (conv1 formula on
// zero-padded x) where conv2's padding requires z1=0. Error at p=0/31, q=0/31
// only: restricted-pair compositions. wct/wcb: (k2h=0,k1h=3)/(k2h=3,k1h=0),
// k=xx*3+ci; wcl/wcr: (k2w=0,k1w=3)/(k2w=3,k1w=0), k=y*3+ci; wcc: 4 corners.
__global__ __launch_bounds__(256) void k_wcorr(const float* __restrict__ w1,
                                               const float* __restrict__ w2,
                                               float* __restrict__ wct, float* __restrict__ wcb,
                                               float* __restrict__ wcl, float* __restrict__ wcr,
                                               float* __restrict__ wcc) {
    int co = blockIdx.x, tid = threadIdx.x;
    if (tid < 30 || (tid >= 32 && tid < 62)) {
        bool top = tid < 30;
        int t = top ? tid : tid - 32;
        int xx = t / 3, ci = t % 3;
        int k2hf = top ? 0 : 3, k1hf = top ? 3 : 0;
        float s = 0.f;
        for (int m = 0; m < 256; ++m)
            for (int k2w = 0; k2w < 4; ++k2w) {
                int k1w = xx - 2 * k2w;
                if ((unsigned)k1w < 4u)
                    s += w2[((co * 256 + m) * 4 + k2hf) * 4 + k2w]
                       * w1[((m * 3 + ci) * 4 + k1hf) * 4 + k1w];
            }
        (top ? wct : wcb)[co * 32 + t] = s;
    } else if ((tid >= 64 && tid < 94) || (tid >= 96 && tid < 126)) {
        bool left = tid < 94;
        int t = left ? tid - 64 : tid - 96;
        int y = t / 3, ci = t % 3;
        int k2wf = left ? 0 : 3, k1wf = left ? 3 : 0;
        float s = 0.f;
        for (int m = 0; m < 256; ++m)
            for (int k2h = 0; k2h < 4; ++k2h) {
                int k1h = y - 2 * k2h;
                if ((unsigned)k1h < 4u)
                    s += w2[((co * 256 + m) * 4 + k2h) * 4 + k2wf]
                       * w1[((m * 3 + ci) * 4 + k1h) * 4 + k1wf];
            }
        (left ? wcl : wcr)[co * 32 + t] = s;
    } else if (tid >= 128 && tid < 140) {
        int c = (tid - 128) / 3, ci = (tid - 128) % 3;
        int k2h = (c >> 1) ? 3 : 0, k2w = (c & 1) ? 3 : 0;
        int k1h = 3 - k2h, k1w = 3 - k2w;
        float s = 0.f;
        for (int m = 0; m < 256; ++m)
            s += w2[((co * 256 + m) * 4 + k2h) * 4 + k2w]
               * w1[((m * 3 + ci) * 4 + k1h) * 4 + k1w];
        wcc[(c * 256 + co) * 4 + ci] = s;
    }
}

// ======================= input packing for composed encoder ====================
// xpk[n][row(128)][ow(32)][k(32)] bf16, k = kw*3+ci (30 used), col = 4*ow-3+kw.
__global__ void k_xpack(const float* __restrict__ x, ushort* __restrict__ xpk) {
    int i = blockIdx.x * 256 + threadIdx.x;     // 4,194,304
    int k = i & 31, ow = (i >> 5) & 31, r = (i >> 10) & 127, n = i >> 17;
    float v = 0.f;
    if (k < 30) {
        int ci = k % 3, kw = k / 3;
        int col = 4 * ow - 3 + kw;
        if ((unsigned)col < 128u) v = x[((n * 3 + ci) * 128 + r) * 128 + col];
    }
    xpk[i] = f2bf(v);
}

// ======================= composed encoder conv: 3->256 k10 s4, 128->32 =========
__global__ __launch_bounds__(128) void k_enc_comp(const ushort* __restrict__ xpk,
                                                  const ushort* __restrict__ wenc,
                                                  const float* __restrict__ benc,
                                                  ushort* __restrict__ obf) {
    int tid = threadIdx.x, lane = tid & 63, wv = tid >> 6;
    int q = lane >> 4, l15 = lane & 15;
    int b = blockIdx.x;
    int mblk = b & 7, coslab = (b >> 3) & 3, n = b >> 5;
    int R0 = mblk * 4 + wv * 2;
    int aoff = (coslab * 64 + l15) * 32 + q * 8;

    f32x4 acc[4][4];
#pragma unroll
    for (int at = 0; at < 4; ++at)
#pragma unroll
        for (int bt = 0; bt < 4; ++bt) acc[at][bt] = 0.f;

    for (int t = 0; t < 10; ++t) {
        bf16x8 af[4];
#pragma unroll
        for (int at = 0; at < 4; ++at)
            af[at] = *(const bf16x8*)(wenc + t * 8192 + aoff + at * 512);
#pragma unroll
        for (int bt2 = 0; bt2 < 2; ++bt2) {
            int irow = 4 * (R0 + bt2) + t - 3;
            if ((unsigned)irow >= 128u) continue;      // x zero padding -> skip
            bf16x8 bf[2];
#pragma unroll
            for (int hb = 0; hb < 2; ++hb) {
                int ow = hb * 16 + l15;
                bf[hb] = *(const bf16x8*)(xpk + (((long)n * 128 + irow) * 32 + ow) * 32 + q * 8);
            }
#pragma unroll
            for (int at = 0; at < 4; ++at)
#pragma unroll
                for (int hb = 0; hb < 2; ++hb)
                    acc[at][bt2 * 2 + hb] = __builtin_amdgcn_mfma_f32_16x16x32_bf16(
                        af[at], bf[hb], acc[at][bt2 * 2 + hb], 0, 0, 0);
        }
    }

    int co_base = coslab * 64;
#pragma unroll
    for (int at = 0; at < 4; ++at) {
        int co_t = co_base + at * 16 + q * 4;
        float4 b4 = *(const float4*)(benc + co_t);
        float bv[4] = {b4.x, b4.y, b4.z, b4.w};
#pragma unroll
        for (int bt = 0; bt < 4; ++bt) {
            int m = R0 * 32 + bt * 16 + l15;
            long oaddr = ((long)n * 1024 + m) * 256 + co_t;
            float v[4];
#pragma unroll
            for (int r = 0; r < 4; ++r) v[r] = acc[at][bt][r] + bv[r];
            uint2 pk;
            pk.x = (unsigned)f2bf(v[0]) | ((unsigned)f2bf(v[1]) << 16);
            pk.y = (unsigned)f2bf(v[2]) | ((unsigned)f2bf(v[3]) << 16);
            *(uint2*)(obf + oaddr) = pk;
        }
    }
}

// ======================= border fix: X0 -= ERR on 124 border px/img ===========
// ERR[p,q] = [p=0]RT + [p=31]RB + [q=0]CL + [q=31]CR - corner double-counts.
// Block = n (32), thread = co (256). Serial RMW per thread -> race-free.
__global__ __launch_bounds__(256) void k_fix_border(const float* __restrict__ x,
                                                    const ushort* __restrict__ xpk,
                                                    const float* __restrict__ wct,
                                                    const float* __restrict__ wcb,
                                                    const float* __restrict__ wcl,
                                                    const float* __restrict__ wcr,
                                                    const float* __restrict__ wcc,
                                                    ushort* __restrict__ X0) {
    int n = blockIdx.x, co = threadIdx.x;
    ushort* base = X0 + (long)n * 1024 * 256 + co;
    auto rmw = [&](int m, float corr) {
        ushort* p = base + (long)m * 256;
        float v = bfl((unsigned)(*p));
        *p = f2bf(v - corr);
    };
    // top (p=0, m=q) and bottom (p=31, m=992+q): dot with xpk rows 0 / 127
    for (int qq = 0; qq < 32; ++qq) {
        float st = 0.f, sb = 0.f;
        const ushort* xt = xpk + (((long)n * 128 + 0) * 32 + qq) * 32;
        const ushort* xb = xpk + (((long)n * 128 + 127) * 32 + qq) * 32;
        for (int k = 0; k < 30; ++k) {
            st += wct[co * 32 + k] * bfl((unsigned)xt[k]);
            sb += wcb[co * 32 + k] * bfl((unsigned)xb[k]);
        }
        rmw(qq, st);
        rmw(992 + qq, sb);
    }
    // left (q=0, m=32p) and right (q=31, m=32p+31): x cols 0 / 127
    for (int p = 0; p < 32; ++p) {
        float sl = 0.f, sr = 0.f;
        for (int y = 0; y < 10; ++y) {
            int row = 4 * p - 3 + y;
            if ((unsigned)row >= 128u) continue;
            for (int ci = 0; ci < 3; ++ci) {
                long xb0 = ((long)(n * 3 + ci) * 128 + row) * 128;
                sl += wcl[co * 32 + y * 3 + ci] * x[xb0];
                sr += wcr[co * 32 + y * 3 + ci] * x[xb0 + 127];
            }
        }
        rmw(32 * p, sl);
        rmw(32 * p + 31, sr);
    }
    // corners: RT and CL both subtracted the (U,V both OOB) term -> add back
    {
        float c00 = 0.f, c03 = 0.f, c30 = 0.f, c33 = 0.f;
        for (int ci = 0; ci < 3; ++ci) {
            long xb0 = ((long)(n * 3 + ci) * 128) * 128;
            c00 += wcc[(0 * 256 + co) * 4 + ci] * x[xb0];
            c03 += wcc[(1 * 256 + co) * 4 + ci] * x[xb0 + 127];
            c30 += wcc[(2 * 256 + co) * 4 + ci] * x[xb0 + 127 * 128];
            c33 += wcc[(3 * 256 + co) * 4 + ci] * x[xb0 + 127 * 128 + 127];
        }
        rmw(0, -c00); rmw(31, -c03); rmw(992, -c30); rmw(1023, -c33);
    }
}

// ======================= fused res block (R15-verified tiling) =================
__global__ __launch_bounds__(256, 2) void k_resblock(const ushort* __restrict__ xin,
                                                     const ushort* __restrict__ w3pk,
                                                     const ushort* __restrict__ w1pk,
                                                     ushort* __restrict__ obf) {
    constexpr int BUFU = 4 * 4 * 34 * 8;             // 4352 ushorts = 8704 B
    __shared__ __align__(16) ushort sX[2 * BUFU];    // 17408 B staging
    __shared__ __align__(16) ushort sEx[64 * 256];   // 32768 B exchange

    int tid = threadIdx.x, lane = tid & 63, wv = tid >> 6;
    int q = lane >> 4, l15 = lane & 15;
    int b = blockIdx.x;                              // 32n * 16 rowpairs
    int rp = b & 15, n = b >> 4;
    int R0 = rp * 2;

    if (tid < 64) {
        int bufi = tid >> 5, rq = (tid >> 1) & 15, cc = (tid & 1) ? 33 : 0;
        uint4 z; z.x = z.y = z.z = z.w = 0;
        *(uint4*)&sX[bufi * BUFU + (rq * 34 + cc) * 8] = z;
    }

    int brr[4], bcol[4];
#pragma unroll
    for (int bt = 0; bt < 4; ++bt) {
        int p = bt * 16 + l15;
        brr[bt] = p >> 5; bcol[bt] = (p & 31) + 1;
    }

    int scol = lane >> 1, j0 = (lane & 1) * 2;
    int aoff = (wv * 64 + l15) * 32 + q * 8;

    f32x4 acc[4][4];
#pragma unroll
    for (int at = 0; at < 4; ++at)
#pragma unroll
        for (int bt = 0; bt < 4; ++bt) acc[at][bt] = 0.f;

    int hh = R0 - 1 + wv;
    bool hvalid = (unsigned)hh < 32u;
    uint4 sreg[2];
    auto stage_load = [&](int cb2) {
        long off = (((long)n * 32 + hh) * 32 + scol) * 256 + cb2 * 32 + j0 * 8;
#pragma unroll
        for (int k = 0; k < 2; ++k) {
            uint4 v;
            if (hvalid) v = relu4(*(const uint4*)(xin + off + k * 8));
            else { v.x = 0; v.y = 0; v.z = 0; v.w = 0; }
            sreg[k] = v;
        }
    };
    auto write_stage = [&](int pbuf) {
        ushort* bufp = sX + pbuf * BUFU;
#pragma unroll
        for (int k = 0; k < 2; ++k)
            *(uint4*)&bufp[((wv * 4 + j0 + k) * 34 + scol + 1) * 8] = sreg[k];
    };

    stage_load(0);
    write_stage(0);
    __syncthreads();

    for (int cb = 0; cb < 8; ++cb) {
        ushort* bufp = sX + (cb & 1) * BUFU;
        if (cb + 1 < 8) stage_load(cb + 1);
        const ushort* wb = w3pk + (long)cb * 8192 + aoff;

        bf16x8 afc[4];
#pragma unroll
        for (int at = 0; at < 4; ++at) afc[at] = *(const bf16x8*)(wb + at * 512);
#pragma unroll
        for (int t = 0; t < 9; ++t) {
            bf16x8 afn[4];
            if (t < 8) {
#pragma unroll
                for (int at = 0; at < 4; ++at)
                    afn[at] = *(const bf16x8*)(wb + (long)(t + 1) * 65536 + at * 512);
            }
            int taprow = t / 3, dx = t % 3 - 1;
            bf16x8 bfr[4];
#pragma unroll
            for (int bt = 0; bt < 4; ++bt)
                bfr[bt] = *(const bf16x8*)&bufp[(((brr[bt] + taprow) * 4 + q) * 34 + bcol[bt] + dx) * 8];
#pragma unroll
            for (int at = 0; at < 4; ++at)
#pragma unroll
                for (int bt = 0; bt < 4; ++bt)
                    acc[at][bt] = __builtin_amdgcn_mfma_f32_16x16x32_bf16(afc[at], bfr[bt],
                                                                          acc[at][bt], 0, 0, 0);
            if (t < 8) {
#pragma unroll
                for (int at = 0; at < 4; ++at) afc[at] = afn[at];
            }
        }

        if (cb + 1 < 8) {
            write_stage((cb + 1) & 1);
            __syncthreads();
        }
    }

#pragma unroll
    for (int at = 0; at < 4; ++at) {
        int co_t = wv * 64 + at * 16 + q * 4;
#pragma unroll
        for (int bt = 0; bt < 4; ++bt) {
            int px = bt * 16 + l15;
            uint2 pk;
            pk.x = (unsigned)f2bf(fmaxf(acc[at][bt][0], 0.f))
                 | ((unsigned)f2bf(fmaxf(acc[at][bt][1], 0.f)) << 16);
            pk.y = (unsigned)f2bf(fmaxf(acc[at][bt][2], 0.f))
                 | ((unsigned)f2bf(fmaxf(acc[at][bt][3], 0.f)) << 16);
            *(uint2*)&sEx[px * 256 + (co_t ^ ((px & 7) << 3))] = pk;
        }
    }
    __syncthreads();

    f32x4 acc2[4][4];
#pragma unroll
    for (int at = 0; at < 4; ++at)
#pragma unroll
        for (int bt = 0; bt < 4; ++bt) acc2[at][bt] = 0.f;

    for (int cb = 0; cb < 8; ++cb) {
        const ushort* wb1 = w1pk + (long)cb * 8192 + aoff;
        bf16x8 af1[4];
#pragma unroll
        for (int at = 0; at < 4; ++at) af1[at] = *(const bf16x8*)(wb1 + at * 512);
        bf16x8 bf1[4];
#pragma unroll
        for (int bt = 0; bt < 4; ++bt) {
            int px = bt * 16 + l15;
            bf1[bt] = *(const bf16x8*)&sEx[px * 256 + ((cb * 32 + q * 8) ^ ((px & 7) << 3))];
        }
#pragma unroll
        for (int at = 0; at < 4; ++at)
#pragma unroll
            for (int bt = 0; bt < 4; ++bt)
                acc2[at][bt] = __builtin_amdgcn_mfma_f32_16x16x32_bf16(af1[at], bf1[bt],
                                                                      acc2[at][bt], 0, 0, 0);
    }

#pragma unroll
    for (int at = 0; at < 4; ++at) {
        int co_t = wv * 64 + at * 16 + q * 4;
#pragma unroll
        for (int bt = 0; bt < 4; ++bt) {
            int m = R0 * 32 + bt * 16 + l15;
            long oaddr = ((long)n * 1024 + m) * 256 + co_t;
            uint2 rr = *(const uint2*)(xin + oaddr);
            float v[4];
            v[0] = acc2[at][bt][0] + bfl(rr.x);
            v[1] = acc2[at][bt][1] + bfh(rr.x);
            v[2] = acc2[at][bt][2] + bfl(rr.y);
            v[3] = acc2[at][bt][3] + bfh(rr.y);
            uint2 pk;
            pk.x = (unsigned)f2bf(v[0]) | ((unsigned)f2bf(v[1]) << 16);
            pk.y = (unsigned)f2bf(v[2]) | ((unsigned)f2bf(v[3]) << 16);
            *(uint2*)(obf + oaddr) = pk;
        }
    }
}

// ======================= VQ via MFMA (bf16 out) =======================
__global__ __launch_bounds__(256) void k_vq2(const ushort* __restrict__ zb,
                                             const ushort* __restrict__ apk,
                                             const float* __restrict__ en,
                                             const float* __restrict__ cbf,
                                             ushort* __restrict__ vqb,
                                             float* __restrict__ loss) {
    __shared__ int sIdx[64];
    __shared__ float sLoss[64];
    int tid = threadIdx.x, lane = tid & 63, wv = tid >> 6;
    int q = lane >> 4, l15 = lane & 15;
    int r0 = blockIdx.x * 64;
    int R = r0 + wv * 16;

    const ushort* zp = zb + ((long)(R + l15)) * 64 + q * 8;
    bf16x8 b0 = *(const bf16x8*)zp;
    bf16x8 b1 = *(const bf16x8*)(zp + 32);

    float z2 = 0.f;
    {
        const unsigned* u0 = (const unsigned*)&b0;
        const unsigned* u1 = (const unsigned*)&b1;
#pragma unroll
        for (int i = 0; i < 4; ++i) {
            float a = bfl(u0[i]), bb = bfh(u0[i]);
            float c = bfl(u1[i]), d = bfh(u1[i]);
            z2 += a * a + bb * bb + c * c + d * d;
        }
    }

    float best = 3.4e38f;
    int bidx = 0;
#pragma unroll
    for (int t = 0; t < 16; ++t) {
        bf16x8 a0 = *(const bf16x8*)(apk + ((t * 2 + 0) * 64 + lane) * 8);
        bf16x8 a1 = *(const bf16x8*)(apk + ((t * 2 + 1) * 64 + lane) * 8);
        f32x4 acc = {0.f, 0.f, 0.f, 0.f};
        acc = __builtin_amdgcn_mfma_f32_16x16x32_bf16(a0, b0, acc, 0, 0, 0);
        acc = __builtin_amdgcn_mfma_f32_16x16x32_bf16(a1, b1, acc, 0, 0, 0);
        float4 e4 = *(const float4*)(en + t * 16 + q * 4);
        float sc[4] = {e4.x - 2.f * acc[0], e4.y - 2.f * acc[1],
                       e4.z - 2.f * acc[2], e4.w - 2.f * acc[3]};
#pragma unroll
        for (int r = 0; r < 4; ++r) {
            int code = t * 16 + q * 4 + r;
            if (sc[r] < best) { best = sc[r]; bidx = code; }
        }
    }
#pragma unroll
    for (int m = 16; m <= 32; m <<= 1) {
        float ob = __shfl_xor(best, m);
        int oi = __shfl_xor(bidx, m);
        if (ob < best || (ob == best && oi < bidx)) { best = ob; bidx = oi; }
        z2 += __shfl_xor(z2, m);
    }
    if (q == 0) {
        sIdx[wv * 16 + l15] = bidx;
        sLoss[wv * 16 + l15] = best + z2;
    }
    __syncthreads();

    if (wv == 0) {
        float l = sLoss[lane];
#pragma unroll
        for (int m = 1; m < 64; m <<= 1) l += __shfl_xor(l, m);
        if (lane == 0) atomicAdd(loss, l * (1.25f / 8388608.f));
    }

    unsigned* vb = (unsigned*)(vqb + (long)r0 * 64);
#pragma unroll
    for (int k = 0; k < 8; ++k) {
        int i = k * 256 + tid;
        int rl = i >> 5, jp = i & 31;
        int idx = sIdx[rl];
        float v0 = cbf[idx * 64 + 2 * jp];
        float v1 = cbf[idx * 64 + 2 * jp + 1];
        vb[i] = (unsigned)f2bf(v0) | ((unsigned)f2bf(v1) << 16);
    }
}

// ======================= composed decoder deconv: 256->3 k10 s4, 32->128 ========
__global__ __launch_bounds__(128, 2) void k_dec_comp(const ushort* __restrict__ xin,
                                                     const ushort* __restrict__ wdec,
                                                     const float* __restrict__ bdec,
                                                     float* __restrict__ out) {
    constexpr int BUFU = 3 * 4 * 34 * 8;             // 3264 ushorts
    constexpr int WLDS = 2 * BUFU;
    __shared__ __align__(16) ushort sX[2 * WLDS];    // 26112 B

    int tid = threadIdx.x, lane = tid & 63, wv = tid >> 6;
    int q = lane >> 4, l15 = lane & 15;
    int b = blockIdx.x;                              // 32n * 16rp
    int rp = b & 15, n = b >> 4;
    int U = rp * 2 + wv;
    ushort* sW = sX + wv * WLDS;

    if (lane < 48) {
        int cc = (lane & 1) ? 33 : 0;
        int sq = lane >> 1;
        uint4 z; z.x = z.y = z.z = z.w = 0;
        *(uint4*)&sW[(sq * 34 + cc) * 8] = z;
    }
    int scol = lane >> 1, j0 = (lane & 1) * 2;

    f32x4 acc[3][2];
#pragma unroll
    for (int o = 0; o < 3; ++o)
#pragma unroll
        for (int bt = 0; bt < 2; ++bt) acc[o][bt] = 0.f;

    uint4 sreg[3][2];
    auto stage_load = [&](int cb2) {
#pragma unroll
        for (int r = 0; r < 3; ++r) {
            int hh = U - 1 + r;
            bool valid = (unsigned)hh < 32u;
            long off = (((long)n * 32 + hh) * 32 + scol) * 256 + cb2 * 32 + j0 * 8;
#pragma unroll
            for (int k = 0; k < 2; ++k) {
                uint4 v;
                if (valid) v = *(const uint4*)(xin + off + k * 8);
                else { v.x = 0; v.y = 0; v.z = 0; v.w = 0; }
                sreg[r][k] = v;
            }
        }
    };
    auto write_stage = [&](int pbuf) {
        ushort* bufp = sW + pbuf * BUFU;
#pragma unroll
        for (int r = 0; r < 3; ++r)
#pragma unroll
            for (int k = 0; k < 2; ++k)
                *(uint4*)&bufp[((r * 4 + j0 + k) * 34 + scol + 1) * 8] = sreg[r][k];
    };

    stage_load(0);
    write_stage(0);

    for (int cb = 0; cb < 8; ++cb) {
        ushort* bufp = sW + (cb & 1) * BUFU;
        if (cb + 1 < 8) stage_load(cb + 1);
        const ushort* wb = wdec + (long)cb * 512 + l15 * 32 + q * 8;
#pragma unroll
        for (int t = 0; t < 9; ++t) {
            int du = t / 3 - 1, dv = t % 3 - 1;
            bf16x8 bfr[2];
#pragma unroll
            for (int bt = 0; bt < 2; ++bt)
                bfr[bt] = *(const bf16x8*)&bufp[(((du + 1) * 4 + q) * 34 + bt * 16 + l15 + 1 + dv) * 8];
#pragma unroll
            for (int o = 0; o < 3; ++o) {
                bf16x8 af = *(const bf16x8*)(wb + (long)(t * 3 + o) * 4096);
#pragma unroll
                for (int bt = 0; bt < 2; ++bt)
                    acc[o][bt] = __builtin_amdgcn_mfma_f32_16x16x32_bf16(af, bfr[bt], acc[o][bt], 0, 0, 0);
            }
        }
        if (cb + 1 < 8) write_stage((cb + 1) & 1);
    }

#pragma unroll
    for (int o = 0; o < 3; ++o) {
#pragma unroll
        for (int bt = 0; bt < 2; ++bt) {
            int V = bt * 16 + l15;
#pragma unroll
            for (int r = 0; r < 4; ++r) {
                int p = q * 4 + r, py = p >> 2, px = p & 3;
                out[(((long)n * 3 + o) * 128 + 4 * U + py) * 128 + 4 * V + px] =
                    tanhf(acc[o][bt][r] + bdec[o * 16 + p]);
            }
        }
    }
}

// ======================= launcher =======================
extern "C" void kernel_launch(void* const* d_in, const int* in_sizes, int n_in,
                              void* d_out, int out_size, void* d_ws, size_t ws_size,
                              hipStream_t stream) {
    (void)in_sizes; (void)n_in; (void)out_size; (void)ws_size;
    const float* x        = (const float*)d_in[0];
    const float* enc_w1   = (const float*)d_in[1];
    const float* enc_b1   = (const float*)d_in[2];
    const float* enc_w2   = (const float*)d_in[3];
    const float* enc_b2   = (const float*)d_in[4];
    const float* er1_w3   = (const float*)d_in[5];
    const float* er1_w1   = (const float*)d_in[6];
    const float* er2_w3   = (const float*)d_in[7];
    const float* er2_w1   = (const float*)d_in[8];
    const float* codebook = (const float*)d_in[9];
    const float* dr1_w3   = (const float*)d_in[10];
    const float* dr1_w1   = (const float*)d_in[11];
    const float* dr2_w3   = (const float*)d_in[12];
    const float* dr2_w1   = (const float*)d_in[13];
    const float* dt1_w    = (const float*)d_in[14];
    const float* dt1_b    = (const float*)d_in[15];
    const float* dt2_w    = (const float*)d_in[16];
    const float* dt2_b    = (const float*)d_in[17];

    float* recon = (float*)d_out;
    float* loss  = recon + 1572864;

    char* ws = (char*)d_ws;
    size_t off = 0;
    auto alloc = [&](size_t bytes) { char* p = ws + off; off += (bytes + 255) & ~(size_t)255; return p; };
    ushort* X0   = (ushort*)alloc(16777216);   // bf16 NHWC 32x32 tensors
    ushort* X2   = (ushort*)alloc(16777216);
    ushort* X3   = (ushort*)alloc(16777216);
    ushort* X4   = (ushort*)alloc(16777216);
    ushort* xpk  = (ushort*)alloc(8388608);    // [32][128][32][32] bf16
    ushort* wpk_er13 = (ushort*)alloc(1179648);
    ushort* wpk_er23 = (ushort*)alloc(1179648);
    ushort* wpk_dr13 = (ushort*)alloc(1179648);
    ushort* wpk_dr23 = (ushort*)alloc(1179648);
    ushort* wpk_er11 = (ushort*)alloc(131072);
    ushort* wpk_er21 = (ushort*)alloc(131072);
    ushort* wpk_dr11 = (ushort*)alloc(131072);
    ushort* wpk_dr21 = (ushort*)alloc(131072);
    ushort* wenc     = (ushort*)alloc(163840); // [10][256][32] bf16
    ushort* wdec     = (ushort*)alloc(221184); // [9][3][8][16][32] bf16
    ushort* apk      = (ushort*)alloc(32768);
    float*  benc     = (float*)alloc(1024);
    float*  bdec     = (float*)alloc(192);
    float*  en       = (float*)alloc(1024);
    float*  wct      = (float*)alloc(32768);
    float*  wcb      = (float*)alloc(32768);
    float*  wcl      = (float*)alloc(32768);
    float*  wcr      = (float*)alloc(32768);
    float*  wcc      = (float*)alloc(16384);

    hipMemsetAsync(loss, 0, sizeof(float), stream);
    hipMemsetAsync(wdec, 0, 221184, stream);

    // weight packing / composition
    k_pack_c3x4<<<9216, 256, 0, stream>>>(er1_w3, er2_w3, dr1_w3, dr2_w3,
                                          wpk_er13, wpk_er23, wpk_dr13, wpk_dr23);
    k_pack_c1x1x4<<<1024, 256, 0, stream>>>(er1_w1, er2_w1, dr1_w1, dr2_w1,
                                            wpk_er11, wpk_er21, wpk_dr11, wpk_dr21);
    k_pack_vq<<<65, 256, 0, stream>>>(codebook, apk, en);
    k_wcomp_enc<<<256, 256, 0, stream>>>(enc_w1, enc_b1, enc_w2, enc_b2, wenc, benc);
    k_wcomp_dec<<<256, 256, 0, stream>>>(dt1_w, dt1_b, dt2_w, dt2_b, wdec, bdec);
    k_wcorr<<<256, 256, 0, stream>>>(enc_w1, enc_w2, wct, wcb, wcl, wcr, wcc);
    k_xpack<<<16384, 256, 0, stream>>>(x, xpk);

    // encoder (composed conv1∘conv2) + exact border fix: x -> X0
    k_enc_comp<<<1024, 128, 0, stream>>>(xpk, wenc, benc, X0);
    k_fix_border<<<32, 256, 0, stream>>>(x, xpk, wct, wcb, wcl, wcr, wcc, X0);
    // fused res blocks (encoder)
    k_resblock<<<512, 256, 0, stream>>>(X0, wpk_er13, wpk_er11, X2);
    k_resblock<<<512, 256, 0, stream>>>(X2, wpk_er23, wpk_er21, X3);
    // VQ: X3 -> X4 (vq, no relu) + loss
    k_vq2<<<2048, 256, 0, stream>>>(X3, apk, en, codebook, X4, loss);
    // fused res blocks (decoder)
    k_resblock<<<512, 256, 0, stream>>>(X4, wpk_dr13, wpk_dr11, X0);
    k_resblock<<<512, 256, 0, stream>>>(X0, wpk_dr23, wpk_dr21, X2);
    // decoder (composed deconv1∘deconv2 + tanh): X2 -> recon
    k_dec_comp<<<512, 128, 0, stream>>>(X2, wdec, bdec, recon);
}

// Round 6
// 607.775 us; speedup vs baseline: 1.2623x; 1.1030x over previous
//
#include <hip/hip_runtime.h>
#include <math.h>

// VQ-VAE forward. R18: k_wcorr (97 µs, #1 dispatch, latency-bound serial
// global-read loops) folded into k_wcomp_enc where w1/w2[co] are already in
// LDS — identical sums, same accumulation order, ~2 µs. Correction tables
// transposed to [k][co] so k_fix_border reads coalesce. Everything else
// byte-identical to R17 (passing, absmax 0.0189).

typedef unsigned short ushort;
typedef short bf16x8 __attribute__((ext_vector_type(8)));
typedef float f32x4 __attribute__((ext_vector_type(4)));

__device__ __forceinline__ ushort f2bf(float f) {
    unsigned u = __builtin_bit_cast(unsigned, f);
    unsigned r = (u + 0x7fffu + ((u >> 16) & 1u)) >> 16;
    return (ushort)r;
}
__device__ __forceinline__ float bfl(unsigned u) { return __builtin_bit_cast(float, u << 16); }
__device__ __forceinline__ float bfh(unsigned u) { return __builtin_bit_cast(float, u & 0xffff0000u); }

__device__ __forceinline__ unsigned relu_u(unsigned u) {
    unsigned m = (u >> 15) & 0x00010001u;
    return u & ~((m << 16) - m);
}
__device__ __forceinline__ uint4 relu4(uint4 v) {
    v.x = relu_u(v.x); v.y = relu_u(v.y); v.z = relu_u(v.z); v.w = relu_u(v.w);
    return v;
}

// ======================= weight packing (res blocks, VQ) =======================
__global__ void k_pack_c3x4(const float* __restrict__ w0, const float* __restrict__ w1,
                            const float* __restrict__ w2, const float* __restrict__ w3,
                            ushort* __restrict__ o0, ushort* __restrict__ o1,
                            ushort* __restrict__ o2, ushort* __restrict__ o3) {
    int layer = blockIdx.x / 2304;
    int i = (blockIdx.x - layer * 2304) * 256 + threadIdx.x;     // 589824
    const float* w = layer == 0 ? w0 : layer == 1 ? w1 : layer == 2 ? w2 : w3;
    ushort* o = layer == 0 ? o0 : layer == 1 ? o1 : layer == 2 ? o2 : o3;
    int kk = i & 31, co = (i >> 5) & 255, cb = (i >> 13) & 7, t = i >> 16;
    int ci = cb * 32 + kk, kh = t / 3, kw = t % 3;
    o[i] = f2bf(w[((co * 256 + ci) * 3 + kh) * 3 + kw]);
}

__global__ void k_pack_c1x1x4(const float* __restrict__ w0, const float* __restrict__ w1,
                              const float* __restrict__ w2, const float* __restrict__ w3,
                              ushort* __restrict__ o0, ushort* __restrict__ o1,
                              ushort* __restrict__ o2, ushort* __restrict__ o3) {
    int layer = blockIdx.x >> 8;
    int i = (blockIdx.x & 255) * 256 + threadIdx.x;              // 65536
    const float* w = layer == 0 ? w0 : layer == 1 ? w1 : layer == 2 ? w2 : w3;
    ushort* o = layer == 0 ? o0 : layer == 1 ? o1 : layer == 2 ? o2 : o3;
    int kk = i & 31, co = (i >> 5) & 255, cb = (i >> 13) & 7;
    o[i] = f2bf(w[co * 256 + cb * 32 + kk]);
}

__global__ void k_pack_vq(const float* __restrict__ cb, ushort* __restrict__ apk,
                          float* __restrict__ en) {
    if (blockIdx.x < 64) {
        int i = blockIdx.x * 256 + threadIdx.x;
        int j = i & 7, lane = (i >> 3) & 63, s = (i >> 9) & 1, t = i >> 10;
        int code = t * 16 + (lane & 15);
        int dim = s * 32 + (lane >> 4) * 8 + j;
        apk[i] = f2bf(cb[code * 64 + dim]);
    } else {
        int code = threadIdx.x;
        float s = 0.f;
        for (int d = 0; d < 64; ++d) { float v = cb[code * 64 + d]; s += v * v; }
        en[code] = s;
    }
}

// ======================= encoder weight composition + border-corr weights ======
// W_eff[co,ci,y,x] = sum_{2k2h+k1h=y} sum_{2k2w+k1w=x} sum_m w2[co,m,k2h,k2w]*w1[m,ci,k1h,k1w]
// packed wenc[y(10)][co(256)][k(32)], k = xx*3+ci (30 used, 2 zeroed).
// Correction weights (for conv2's z1 zero-padding vs virtual-row composition),
// computed here from the LDS-staged sw1/sw2 (was k_wcorr: 97 µs of serial
// global reads). Transposed layouts for coalesced k_fix_border reads:
// wct/wcb[k(30)][co], wcl/wcr[y*3+ci(30)][co], wcc[c*3+ci(12)][co].
__global__ __launch_bounds__(256) void k_wcomp_enc(const float* __restrict__ w1,
                                                   const float* __restrict__ b1f,
                                                   const float* __restrict__ w2,
                                                   const float* __restrict__ b2f,
                                                   ushort* __restrict__ wenc,
                                                   float* __restrict__ benc,
                                                   float* __restrict__ wct,
                                                   float* __restrict__ wcb,
                                                   float* __restrict__ wcl,
                                                   float* __restrict__ wcr,
                                                   float* __restrict__ wcc) {
    __shared__ float sw1[12288];   // w1[m][ci][k1h][k1w]
    __shared__ float sw2[4096];    // w2[co][m][k2h][k2w]
    __shared__ float part[2400];
    int co = blockIdx.x, tid = threadIdx.x;
    for (int i = tid; i < 12288; i += 256) sw1[i] = w1[i];
    for (int i = tid; i < 4096; i += 256) sw2[i] = w2[co * 4096 + i];
    __syncthreads();

    {   // bias (exact since b1=0; interior formula)
        float s = 0.f;
#pragma unroll
        for (int t = 0; t < 16; ++t) s += sw2[tid * 16 + t];
        float pb = b1f[tid] * s;
#pragma unroll
        for (int m = 1; m < 64; m <<= 1) pb += __shfl_xor(pb, m);
        if ((tid & 63) == 0) part[tid >> 6] = pb;
    }
    __syncthreads();
    if (tid == 0) benc[co] = b2f[co] + part[0] + part[1] + part[2] + part[3];

    if (tid < 240) {               // t = y*24 + ci*8 + ms
        int y = tid / 24, rem = tid % 24, ci = rem / 8, ms = rem % 8;
        int na = 0, aa[2], h1[2];
#pragma unroll
        for (int a = 0; a < 4; ++a) {
            int k1 = y - 2 * a;
            if ((unsigned)k1 < 4u) { aa[na] = a; h1[na] = k1; ++na; }
        }
        float acc10[10];
#pragma unroll
        for (int xx = 0; xx < 10; ++xx) acc10[xx] = 0.f;
        for (int m = ms * 32; m < ms * 32 + 32; ++m) {
            for (int pa = 0; pa < na; ++pa) {
                float4 a2 = *(const float4*)&sw2[m * 16 + aa[pa] * 4];
                float4 a1 = *(const float4*)&sw1[m * 48 + ci * 16 + h1[pa] * 4];
                // acc10[2*k2w + k1w] += a2[k2w] * a1[k1w]
                acc10[0] += a2.x * a1.x; acc10[1] += a2.x * a1.y; acc10[2] += a2.x * a1.z; acc10[3] += a2.x * a1.w;
                acc10[2] += a2.y * a1.x; acc10[3] += a2.y * a1.y; acc10[4] += a2.y * a1.z; acc10[5] += a2.y * a1.w;
                acc10[4] += a2.z * a1.x; acc10[5] += a2.z * a1.y; acc10[6] += a2.z * a1.z; acc10[7] += a2.z * a1.w;
                acc10[6] += a2.w * a1.x; acc10[7] += a2.w * a1.y; acc10[8] += a2.w * a1.z; acc10[9] += a2.w * a1.w;
            }
        }
#pragma unroll
        for (int xx = 0; xx < 10; ++xx) part[tid * 10 + xx] = acc10[xx];
    }
    __syncthreads();
    // grid-stride writer tail (R17 fix)
    for (int w = tid; w < 320; w += 256) {
        if (w < 300) {
            int y = w / 30, r = w % 30, ci = r / 10, xx = r % 10;
            float s = 0.f;
#pragma unroll
            for (int ms = 0; ms < 8; ++ms) s += part[((y * 24 + ci * 8) + ms) * 10 + xx];
            wenc[(y * 256 + co) * 32 + xx * 3 + ci] = f2bf(s);
        } else {
            int j = w - 300;
            int y = j >> 1;
            wenc[(y * 256 + co) * 32 + 30 + (j & 1)] = 0;
        }
    }

    // ---- border-correction weights from LDS (same sums as old k_wcorr) ----
    if (tid < 30 || (tid >= 32 && tid < 62)) {
        bool top = tid < 30;
        int t = top ? tid : tid - 32;
        int xx = t / 3, ci = t % 3;
        int k2hf = top ? 0 : 3, k1hf = top ? 3 : 0;
        float s = 0.f;
        for (int m = 0; m < 256; ++m)
            for (int k2w = 0; k2w < 4; ++k2w) {
                int k1w = xx - 2 * k2w;
                if ((unsigned)k1w < 4u)
                    s += sw2[m * 16 + k2hf * 4 + k2w] * sw1[m * 48 + ci * 16 + k1hf * 4 + k1w];
            }
        (top ? wct : wcb)[t * 256 + co] = s;
    } else if ((tid >= 64 && tid < 94) || (tid >= 96 && tid < 126)) {
        bool left = tid < 94;
        int t = left ? tid - 64 : tid - 96;
        int y = t / 3, ci = t % 3;
        int k2wf = left ? 0 : 3, k1wf = left ? 3 : 0;
        float s = 0.f;
        for (int m = 0; m < 256; ++m)
            for (int k2h = 0; k2h < 4; ++k2h) {
                int k1h = y - 2 * k2h;
                if ((unsigned)k1h < 4u)
                    s += sw2[m * 16 + k2h * 4 + k2wf] * sw1[m * 48 + ci * 16 + k1h * 4 + k1wf];
            }
        (left ? wcl : wcr)[t * 256 + co] = s;
    } else if (tid >= 128 && tid < 140) {
        int c = (tid - 128) / 3, ci = (tid - 128) % 3;
        int k2h = (c >> 1) ? 3 : 0, k2w = (c & 1) ? 3 : 0;
        int k1h = 3 - k2h, k1w = 3 - k2w;
        float s = 0.f;
        for (int m = 0; m < 256; ++m)
            s += sw2[m * 16 + k2h * 4 + k2w] * sw1[m * 48 + ci * 16 + k1h * 4 + k1w];
        wcc[(c * 3 + ci) * 256 + co] = s;
    }
}

// ======================= decoder weight composition =======================
__global__ __launch_bounds__(256) void k_wcomp_dec(const float* __restrict__ dt1,
                                                   const float* __restrict__ dt1b,
                                                   const float* __restrict__ dt2,
                                                   const float* __restrict__ dt2b,
                                                   ushort* __restrict__ wdec,
                                                   float* __restrict__ bdec) {
    __shared__ float s1[4096];
    __shared__ float s2[12288];
    __shared__ float part[2400];
    int ci = blockIdx.x, tid = threadIdx.x;
    for (int i = tid; i < 4096; i += 256) s1[i] = dt1[ci * 4096 + i];
    for (int i = tid; i < 12288; i += 256) s2[i] = dt2[i];
    __syncthreads();

    if (ci == 0 && tid < 48) {
        int o = tid >> 4, p = tid & 15, py = p >> 2, px = p & 3;
        int c0 = (py + 1) & 1, d0 = (px + 1) & 1;
        float s = dt2b[o];
        for (int m = 0; m < 256; ++m) {
            float t2 = s2[m * 48 + o * 16 + c0 * 4 + d0] + s2[m * 48 + o * 16 + c0 * 4 + d0 + 2]
                     + s2[m * 48 + o * 16 + (c0 + 2) * 4 + d0] + s2[m * 48 + o * 16 + (c0 + 2) * 4 + d0 + 2];
            s += dt1b[m] * t2;
        }
        bdec[tid] = s;
    }

    if (tid < 240) {
        int y = tid / 24, rem = tid % 24, o = rem / 8, ms = rem % 8;
        int na = 0, aa[2], cc[2];
#pragma unroll
        for (int a = 0; a < 4; ++a) {
            int c = y - 2 * a;
            if ((unsigned)c < 4u) { aa[na] = a; cc[na] = c; ++na; }
        }
        float acc10[10];
#pragma unroll
        for (int xx = 0; xx < 10; ++xx) acc10[xx] = 0.f;
        for (int m = ms * 32; m < ms * 32 + 32; ++m) {
            for (int pa = 0; pa < na; ++pa) {
                float4 d1 = *(const float4*)&s1[m * 16 + aa[pa] * 4];
                float4 d2 = *(const float4*)&s2[m * 48 + o * 16 + cc[pa] * 4];
                acc10[0] += d1.x * d2.x; acc10[1] += d1.x * d2.y; acc10[2] += d1.x * d2.z; acc10[3] += d1.x * d2.w;
                acc10[2] += d1.y * d2.x; acc10[3] += d1.y * d2.y; acc10[4] += d1.y * d2.z; acc10[5] += d1.y * d2.w;
                acc10[4] += d1.z * d2.x; acc10[5] += d1.z * d2.y; acc10[6] += d1.z * d2.z; acc10[7] += d1.z * d2.w;
                acc10[6] += d1.w * d2.x; acc10[7] += d1.w * d2.y; acc10[8] += d1.w * d2.z; acc10[9] += d1.w * d2.w;
            }
        }
#pragma unroll
        for (int xx = 0; xx < 10; ++xx) part[tid * 10 + xx] = acc10[xx];
    }
    __syncthreads();
    for (int w = tid; w < 300; w += 256) {
        int y = w / 30, r = w % 30, o = r / 10, xx = r % 10;
        float s = 0.f;
#pragma unroll
        for (int ms = 0; ms < 8; ++ms) s += part[((y * 24 + o * 8) + ms) * 10 + xx];
        int du = (y < 3) ? 1 : (y < 7) ? 0 : -1;
        int py = y - 3 + 4 * du;
        int dv = (xx < 3) ? 1 : (xx < 7) ? 0 : -1;
        int px = xx - 3 + 4 * dv;
        int t = (du + 1) * 3 + (dv + 1);
        int cb2 = ci >> 5, kk = ci & 31;
        wdec[((((t * 3 + o) * 8 + cb2) * 16 + py * 4 + px) * 32) + kk] = f2bf(s);
    }
}

// ======================= input packing for composed encoder ====================
__global__ void k_xpack(const float* __restrict__ x, ushort* __restrict__ xpk) {
    int i = blockIdx.x * 256 + threadIdx.x;     // 4,194,304
    int k = i & 31, ow = (i >> 5) & 31, r = (i >> 10) & 127, n = i >> 17;
    float v = 0.f;
    if (k < 30) {
        int ci = k % 3, kw = k / 3;
        int col = 4 * ow - 3 + kw;
        if ((unsigned)col < 128u) v = x[((n * 3 + ci) * 128 + r) * 128 + col];
    }
    xpk[i] = f2bf(v);
}

// ======================= composed encoder conv: 3->256 k10 s4, 128->32 =========
__global__ __launch_bounds__(128) void k_enc_comp(const ushort* __restrict__ xpk,
                                                  const ushort* __restrict__ wenc,
                                                  const float* __restrict__ benc,
                                                  ushort* __restrict__ obf) {
    int tid = threadIdx.x, lane = tid & 63, wv = tid >> 6;
    int q = lane >> 4, l15 = lane & 15;
    int b = blockIdx.x;
    int mblk = b & 7, coslab = (b >> 3) & 3, n = b >> 5;
    int R0 = mblk * 4 + wv * 2;
    int aoff = (coslab * 64 + l15) * 32 + q * 8;

    f32x4 acc[4][4];
#pragma unroll
    for (int at = 0; at < 4; ++at)
#pragma unroll
        for (int bt = 0; bt < 4; ++bt) acc[at][bt] = 0.f;

    for (int t = 0; t < 10; ++t) {
        bf16x8 af[4];
#pragma unroll
        for (int at = 0; at < 4; ++at)
            af[at] = *(const bf16x8*)(wenc + t * 8192 + aoff + at * 512);
#pragma unroll
        for (int bt2 = 0; bt2 < 2; ++bt2) {
            int irow = 4 * (R0 + bt2) + t - 3;
            if ((unsigned)irow >= 128u) continue;      // x zero padding -> skip
            bf16x8 bf[2];
#pragma unroll
            for (int hb = 0; hb < 2; ++hb) {
                int ow = hb * 16 + l15;
                bf[hb] = *(const bf16x8*)(xpk + (((long)n * 128 + irow) * 32 + ow) * 32 + q * 8);
            }
#pragma unroll
            for (int at = 0; at < 4; ++at)
#pragma unroll
                for (int hb = 0; hb < 2; ++hb)
                    acc[at][bt2 * 2 + hb] = __builtin_amdgcn_mfma_f32_16x16x32_bf16(
                        af[at], bf[hb], acc[at][bt2 * 2 + hb], 0, 0, 0);
        }
    }

    int co_base = coslab * 64;
#pragma unroll
    for (int at = 0; at < 4; ++at) {
        int co_t = co_base + at * 16 + q * 4;
        float4 b4 = *(const float4*)(benc + co_t);
        float bv[4] = {b4.x, b4.y, b4.z, b4.w};
#pragma unroll
        for (int bt = 0; bt < 4; ++bt) {
            int m = R0 * 32 + bt * 16 + l15;
            long oaddr = ((long)n * 1024 + m) * 256 + co_t;
            float v[4];
#pragma unroll
            for (int r = 0; r < 4; ++r) v[r] = acc[at][bt][r] + bv[r];
            uint2 pk;
            pk.x = (unsigned)f2bf(v[0]) | ((unsigned)f2bf(v[1]) << 16);
            pk.y = (unsigned)f2bf(v[2]) | ((unsigned)f2bf(v[3]) << 16);
            *(uint2*)(obf + oaddr) = pk;
        }
    }
}

// ======================= border fix: X0 -= ERR on 124 border px/img ===========
// Tables now transposed [k][co] -> coalesced reads across the 256 co-threads.
__global__ __launch_bounds__(256) void k_fix_border(const float* __restrict__ x,
                                                    const ushort* __restrict__ xpk,
                                                    const float* __restrict__ wct,
                                                    const float* __restrict__ wcb,
                                                    const float* __restrict__ wcl,
                                                    const float* __restrict__ wcr,
                                                    const float* __restrict__ wcc,
                                                    ushort* __restrict__ X0) {
    int n = blockIdx.x, co = threadIdx.x;
    ushort* base = X0 + (long)n * 1024 * 256 + co;
    auto rmw = [&](int m, float corr) {
        ushort* p = base + (long)m * 256;
        float v = bfl((unsigned)(*p));
        *p = f2bf(v - corr);
    };
    for (int qq = 0; qq < 32; ++qq) {
        float st = 0.f, sb = 0.f;
        const ushort* xt = xpk + (((long)n * 128 + 0) * 32 + qq) * 32;
        const ushort* xb = xpk + (((long)n * 128 + 127) * 32 + qq) * 32;
        for (int k = 0; k < 30; ++k) {
            st += wct[k * 256 + co] * bfl((unsigned)xt[k]);
            sb += wcb[k * 256 + co] * bfl((unsigned)xb[k]);
        }
        rmw(qq, st);
        rmw(992 + qq, sb);
    }
    for (int p = 0; p < 32; ++p) {
        float sl = 0.f, sr = 0.f;
        for (int y = 0; y < 10; ++y) {
            int row = 4 * p - 3 + y;
            if ((unsigned)row >= 128u) continue;
            for (int ci = 0; ci < 3; ++ci) {
                long xb0 = ((long)(n * 3 + ci) * 128 + row) * 128;
                sl += wcl[(y * 3 + ci) * 256 + co] * x[xb0];
                sr += wcr[(y * 3 + ci) * 256 + co] * x[xb0 + 127];
            }
        }
        rmw(32 * p, sl);
        rmw(32 * p + 31, sr);
    }
    {
        float c00 = 0.f, c03 = 0.f, c30 = 0.f, c33 = 0.f;
        for (int ci = 0; ci < 3; ++ci) {
            long xb0 = ((long)(n * 3 + ci) * 128) * 128;
            c00 += wcc[(0 * 3 + ci) * 256 + co] * x[xb0];
            c03 += wcc[(1 * 3 + ci) * 256 + co] * x[xb0 + 127];
            c30 += wcc[(2 * 3 + ci) * 256 + co] * x[xb0 + 127 * 128];
            c33 += wcc[(3 * 3 + ci) * 256 + co] * x[xb0 + 127 * 128 + 127];
        }
        rmw(0, -c00); rmw(31, -c03); rmw(992, -c30); rmw(1023, -c33);
    }
}

// ======================= fused res block (R15-verified tiling) =================
__global__ __launch_bounds__(256, 2) void k_resblock(const ushort* __restrict__ xin,
                                                     const ushort* __restrict__ w3pk,
                                                     const ushort* __restrict__ w1pk,
                                                     ushort* __restrict__ obf) {
    constexpr int BUFU = 4 * 4 * 34 * 8;             // 4352 ushorts = 8704 B
    __shared__ __align__(16) ushort sX[2 * BUFU];    // 17408 B staging
    __shared__ __align__(16) ushort sEx[64 * 256];   // 32768 B exchange

    int tid = threadIdx.x, lane = tid & 63, wv = tid >> 6;
    int q = lane >> 4, l15 = lane & 15;
    int b = blockIdx.x;                              // 32n * 16 rowpairs
    int rp = b & 15, n = b >> 4;
    int R0 = rp * 2;

    if (tid < 64) {
        int bufi = tid >> 5, rq = (tid >> 1) & 15, cc = (tid & 1) ? 33 : 0;
        uint4 z; z.x = z.y = z.z = z.w = 0;
        *(uint4*)&sX[bufi * BUFU + (rq * 34 + cc) * 8] = z;
    }

    int brr[4], bcol[4];
#pragma unroll
    for (int bt = 0; bt < 4; ++bt) {
        int p = bt * 16 + l15;
        brr[bt] = p >> 5; bcol[bt] = (p & 31) + 1;
    }

    int scol = lane >> 1, j0 = (lane & 1) * 2;
    int aoff = (wv * 64 + l15) * 32 + q * 8;

    f32x4 acc[4][4];
#pragma unroll
    for (int at = 0; at < 4; ++at)
#pragma unroll
        for (int bt = 0; bt < 4; ++bt) acc[at][bt] = 0.f;

    int hh = R0 - 1 + wv;
    bool hvalid = (unsigned)hh < 32u;
    uint4 sreg[2];
    auto stage_load = [&](int cb2) {
        long off = (((long)n * 32 + hh) * 32 + scol) * 256 + cb2 * 32 + j0 * 8;
#pragma unroll
        for (int k = 0; k < 2; ++k) {
            uint4 v;
            if (hvalid) v = relu4(*(const uint4*)(xin + off + k * 8));
            else { v.x = 0; v.y = 0; v.z = 0; v.w = 0; }
            sreg[k] = v;
        }
    };
    auto write_stage = [&](int pbuf) {
        ushort* bufp = sX + pbuf * BUFU;
#pragma unroll
        for (int k = 0; k < 2; ++k)
            *(uint4*)&bufp[((wv * 4 + j0 + k) * 34 + scol + 1) * 8] = sreg[k];
    };

    stage_load(0);
    write_stage(0);
    __syncthreads();

    for (int cb = 0; cb < 8; ++cb) {
        ushort* bufp = sX + (cb & 1) * BUFU;
        if (cb + 1 < 8) stage_load(cb + 1);
        const ushort* wb = w3pk + (long)cb * 8192 + aoff;

        bf16x8 afc[4];
#pragma unroll
        for (int at = 0; at < 4; ++at) afc[at] = *(const bf16x8*)(wb + at * 512);
#pragma unroll
        for (int t = 0; t < 9; ++t) {
            bf16x8 afn[4];
            if (t < 8) {
#pragma unroll
                for (int at = 0; at < 4; ++at)
                    afn[at] = *(const bf16x8*)(wb + (long)(t + 1) * 65536 + at * 512);
            }
            int taprow = t / 3, dx = t % 3 - 1;
            bf16x8 bfr[4];
#pragma unroll
            for (int bt = 0; bt < 4; ++bt)
                bfr[bt] = *(const bf16x8*)&bufp[(((brr[bt] + taprow) * 4 + q) * 34 + bcol[bt] + dx) * 8];
#pragma unroll
            for (int at = 0; at < 4; ++at)
#pragma unroll
                for (int bt = 0; bt < 4; ++bt)
                    acc[at][bt] = __builtin_amdgcn_mfma_f32_16x16x32_bf16(afc[at], bfr[bt],
                                                                          acc[at][bt], 0, 0, 0);
            if (t < 8) {
#pragma unroll
                for (int at = 0; at < 4; ++at) afc[at] = afn[at];
            }
        }

        if (cb + 1 < 8) {
            write_stage((cb + 1) & 1);
            __syncthreads();
        }
    }

#pragma unroll
    for (int at = 0; at < 4; ++at) {
        int co_t = wv * 64 + at * 16 + q * 4;
#pragma unroll
        for (int bt = 0; bt < 4; ++bt) {
            int px = bt * 16 + l15;
            uint2 pk;
            pk.x = (unsigned)f2bf(fmaxf(acc[at][bt][0], 0.f))
                 | ((unsigned)f2bf(fmaxf(acc[at][bt][1], 0.f)) << 16);
            pk.y = (unsigned)f2bf(fmaxf(acc[at][bt][2], 0.f))
                 | ((unsigned)f2bf(fmaxf(acc[at][bt][3], 0.f)) << 16);
            *(uint2*)&sEx[px * 256 + (co_t ^ ((px & 7) << 3))] = pk;
        }
    }
    __syncthreads();

    f32x4 acc2[4][4];
#pragma unroll
    for (int at = 0; at < 4; ++at)
#pragma unroll
        for (int bt = 0; bt < 4; ++bt) acc2[at][bt] = 0.f;

    for (int cb = 0; cb < 8; ++cb) {
        const ushort* wb1 = w1pk + (long)cb * 8192 + aoff;
        bf16x8 af1[4];
#pragma unroll
        for (int at = 0; at < 4; ++at) af1[at] = *(const bf16x8*)(wb1 + at * 512);
        bf16x8 bf1[4];
#pragma unroll
        for (int bt = 0; bt < 4; ++bt) {
            int px = bt * 16 + l15;
            bf1[bt] = *(const bf16x8*)&sEx[px * 256 + ((cb * 32 + q * 8) ^ ((px & 7) << 3))];
        }
#pragma unroll
        for (int at = 0; at < 4; ++at)
#pragma unroll
            for (int bt = 0; bt < 4; ++bt)
                acc2[at][bt] = __builtin_amdgcn_mfma_f32_16x16x32_bf16(af1[at], bf1[bt],
                                                                      acc2[at][bt], 0, 0, 0);
    }

#pragma unroll
    for (int at = 0; at < 4; ++at) {
        int co_t = wv * 64 + at * 16 + q * 4;
#pragma unroll
        for (int bt = 0; bt < 4; ++bt) {
            int m = R0 * 32 + bt * 16 + l15;
            long oaddr = ((long)n * 1024 + m) * 256 + co_t;
            uint2 rr = *(const uint2*)(xin + oaddr);
            float v[4];
            v[0] = acc2[at][bt][0] + bfl(rr.x);
            v[1] = acc2[at][bt][1] + bfh(rr.x);
            v[2] = acc2[at][bt][2] + bfl(rr.y);
            v[3] = acc2[at][bt][3] + bfh(rr.y);
            uint2 pk;
            pk.x = (unsigned)f2bf(v[0]) | ((unsigned)f2bf(v[1]) << 16);
            pk.y = (unsigned)f2bf(v[2]) | ((unsigned)f2bf(v[3]) << 16);
            *(uint2*)(obf + oaddr) = pk;
        }
    }
}

// ======================= VQ via MFMA (bf16 out) =======================
__global__ __launch_bounds__(256) void k_vq2(const ushort* __restrict__ zb,
                                             const ushort* __restrict__ apk,
                                             const float* __restrict__ en,
                                             const float* __restrict__ cbf,
                                             ushort* __restrict__ vqb,
                                             float* __restrict__ loss) {
    __shared__ int sIdx[64];
    __shared__ float sLoss[64];
    int tid = threadIdx.x, lane = tid & 63, wv = tid >> 6;
    int q = lane >> 4, l15 = lane & 15;
    int r0 = blockIdx.x * 64;
    int R = r0 + wv * 16;

    const ushort* zp = zb + ((long)(R + l15)) * 64 + q * 8;
    bf16x8 b0 = *(const bf16x8*)zp;
    bf16x8 b1 = *(const bf16x8*)(zp + 32);

    float z2 = 0.f;
    {
        const unsigned* u0 = (const unsigned*)&b0;
        const unsigned* u1 = (const unsigned*)&b1;
#pragma unroll
        for (int i = 0; i < 4; ++i) {
            float a = bfl(u0[i]), bb = bfh(u0[i]);
            float c = bfl(u1[i]), d = bfh(u1[i]);
            z2 += a * a + bb * bb + c * c + d * d;
        }
    }

    float best = 3.4e38f;
    int bidx = 0;
#pragma unroll
    for (int t = 0; t < 16; ++t) {
        bf16x8 a0 = *(const bf16x8*)(apk + ((t * 2 + 0) * 64 + lane) * 8);
        bf16x8 a1 = *(const bf16x8*)(apk + ((t * 2 + 1) * 64 + lane) * 8);
        f32x4 acc = {0.f, 0.f, 0.f, 0.f};
        acc = __builtin_amdgcn_mfma_f32_16x16x32_bf16(a0, b0, acc, 0, 0, 0);
        acc = __builtin_amdgcn_mfma_f32_16x16x32_bf16(a1, b1, acc, 0, 0, 0);
        float4 e4 = *(const float4*)(en + t * 16 + q * 4);
        float sc[4] = {e4.x - 2.f * acc[0], e4.y - 2.f * acc[1],
                       e4.z - 2.f * acc[2], e4.w - 2.f * acc[3]};
#pragma unroll
        for (int r = 0; r < 4; ++r) {
            int code = t * 16 + q * 4 + r;
            if (sc[r] < best) { best = sc[r]; bidx = code; }
        }
    }
#pragma unroll
    for (int m = 16; m <= 32; m <<= 1) {
        float ob = __shfl_xor(best, m);
        int oi = __shfl_xor(bidx, m);
        if (ob < best || (ob == best && oi < bidx)) { best = ob; bidx = oi; }
        z2 += __shfl_xor(z2, m);
    }
    if (q == 0) {
        sIdx[wv * 16 + l15] = bidx;
        sLoss[wv * 16 + l15] = best + z2;
    }
    __syncthreads();

    if (wv == 0) {
        float l = sLoss[lane];
#pragma unroll
        for (int m = 1; m < 64; m <<= 1) l += __shfl_xor(l, m);
        if (lane == 0) atomicAdd(loss, l * (1.25f / 8388608.f));
    }

    unsigned* vb = (unsigned*)(vqb + (long)r0 * 64);
#pragma unroll
    for (int k = 0; k < 8; ++k) {
        int i = k * 256 + tid;
        int rl = i >> 5, jp = i & 31;
        int idx = sIdx[rl];
        float v0 = cbf[idx * 64 + 2 * jp];
        float v1 = cbf[idx * 64 + 2 * jp + 1];
        vb[i] = (unsigned)f2bf(v0) | ((unsigned)f2bf(v1) << 16);
    }
}

// ======================= composed decoder deconv: 256->3 k10 s4, 32->128 ========
__global__ __launch_bounds__(128, 2) void k_dec_comp(const ushort* __restrict__ xin,
                                                     const ushort* __restrict__ wdec,
                                                     const float* __restrict__ bdec,
                                                     float* __restrict__ out) {
    constexpr int BUFU = 3 * 4 * 34 * 8;             // 3264 ushorts
    constexpr int WLDS = 2 * BUFU;
    __shared__ __align__(16) ushort sX[2 * WLDS];    // 26112 B

    int tid = threadIdx.x, lane = tid & 63, wv = tid >> 6;
    int q = lane >> 4, l15 = lane & 15;
    int b = blockIdx.x;                              // 32n * 16rp
    int rp = b & 15, n = b >> 4;
    int U = rp * 2 + wv;
    ushort* sW = sX + wv * WLDS;

    if (lane < 48) {
        int cc = (lane & 1) ? 33 : 0;
        int sq = lane >> 1;
        uint4 z; z.x = z.y = z.z = z.w = 0;
        *(uint4*)&sW[(sq * 34 + cc) * 8] = z;
    }
    int scol = lane >> 1, j0 = (lane & 1) * 2;

    f32x4 acc[3][2];
#pragma unroll
    for (int o = 0; o < 3; ++o)
#pragma unroll
        for (int bt = 0; bt < 2; ++bt) acc[o][bt] = 0.f;

    uint4 sreg[3][2];
    auto stage_load = [&](int cb2) {
#pragma unroll
        for (int r = 0; r < 3; ++r) {
            int hh = U - 1 + r;
            bool valid = (unsigned)hh < 32u;
            long off = (((long)n * 32 + hh) * 32 + scol) * 256 + cb2 * 32 + j0 * 8;
#pragma unroll
            for (int k = 0; k < 2; ++k) {
                uint4 v;
                if (valid) v = *(const uint4*)(xin + off + k * 8);
                else { v.x = 0; v.y = 0; v.z = 0; v.w = 0; }
                sreg[r][k] = v;
            }
        }
    };
    auto write_stage = [&](int pbuf) {
        ushort* bufp = sW + pbuf * BUFU;
#pragma unroll
        for (int r = 0; r < 3; ++r)
#pragma unroll
            for (int k = 0; k < 2; ++k)
                *(uint4*)&bufp[((r * 4 + j0 + k) * 34 + scol + 1) * 8] = sreg[r][k];
    };

    stage_load(0);
    write_stage(0);

    for (int cb = 0; cb < 8; ++cb) {
        ushort* bufp = sW + (cb & 1) * BUFU;
        if (cb + 1 < 8) stage_load(cb + 1);
        const ushort* wb = wdec + (long)cb * 512 + l15 * 32 + q * 8;
#pragma unroll
        for (int t = 0; t < 9; ++t) {
            int du = t / 3 - 1, dv = t % 3 - 1;
            bf16x8 bfr[2];
#pragma unroll
            for (int bt = 0; bt < 2; ++bt)
                bfr[bt] = *(const bf16x8*)&bufp[(((du + 1) * 4 + q) * 34 + bt * 16 + l15 + 1 + dv) * 8];
#pragma unroll
            for (int o = 0; o < 3; ++o) {
                bf16x8 af = *(const bf16x8*)(wb + (long)(t * 3 + o) * 4096);
#pragma unroll
                for (int bt = 0; bt < 2; ++bt)
                    acc[o][bt] = __builtin_amdgcn_mfma_f32_16x16x32_bf16(af, bfr[bt], acc[o][bt], 0, 0, 0);
            }
        }
        if (cb + 1 < 8) write_stage((cb + 1) & 1);
    }

#pragma unroll
    for (int o = 0; o < 3; ++o) {
#pragma unroll
        for (int bt = 0; bt < 2; ++bt) {
            int V = bt * 16 + l15;
#pragma unroll
            for (int r = 0; r < 4; ++r) {
                int p = q * 4 + r, py = p >> 2, px = p & 3;
                out[(((long)n * 3 + o) * 128 + 4 * U + py) * 128 + 4 * V + px] =
                    tanhf(acc[o][bt][r] + bdec[o * 16 + p]);
            }
        }
    }
}

// ======================= launcher =======================
extern "C" void kernel_launch(void* const* d_in, const int* in_sizes, int n_in,
                              void* d_out, int out_size, void* d_ws, size_t ws_size,
                              hipStream_t stream) {
    (void)in_sizes; (void)n_in; (void)out_size; (void)ws_size;
    const float* x        = (const float*)d_in[0];
    const float* enc_w1   = (const float*)d_in[1];
    const float* enc_b1   = (const float*)d_in[2];
    const float* enc_w2   = (const float*)d_in[3];
    const float* enc_b2   = (const float*)d_in[4];
    const float* er1_w3   = (const float*)d_in[5];
    const float* er1_w1   = (const float*)d_in[6];
    const float* er2_w3   = (const float*)d_in[7];
    const float* er2_w1   = (const float*)d_in[8];
    const float* codebook = (const float*)d_in[9];
    const float* dr1_w3   = (const float*)d_in[10];
    const float* dr1_w1   = (const float*)d_in[11];
    const float* dr2_w3   = (const float*)d_in[12];
    const float* dr2_w1   = (const float*)d_in[13];
    const float* dt1_w    = (const float*)d_in[14];
    const float* dt1_b    = (const float*)d_in[15];
    const float* dt2_w    = (const float*)d_in[16];
    const float* dt2_b    = (const float*)d_in[17];

    float* recon = (float*)d_out;
    float* loss  = recon + 1572864;

    char* ws = (char*)d_ws;
    size_t off = 0;
    auto alloc = [&](size_t bytes) { char* p = ws + off; off += (bytes + 255) & ~(size_t)255; return p; };
    ushort* X0   = (ushort*)alloc(16777216);   // bf16 NHWC 32x32 tensors
    ushort* X2   = (ushort*)alloc(16777216);
    ushort* X3   = (ushort*)alloc(16777216);
    ushort* X4   = (ushort*)alloc(16777216);
    ushort* xpk  = (ushort*)alloc(8388608);    // [32][128][32][32] bf16
    ushort* wpk_er13 = (ushort*)alloc(1179648);
    ushort* wpk_er23 = (ushort*)alloc(1179648);
    ushort* wpk_dr13 = (ushort*)alloc(1179648);
    ushort* wpk_dr23 = (ushort*)alloc(1179648);
    ushort* wpk_er11 = (ushort*)alloc(131072);
    ushort* wpk_er21 = (ushort*)alloc(131072);
    ushort* wpk_dr11 = (ushort*)alloc(131072);
    ushort* wpk_dr21 = (ushort*)alloc(131072);
    ushort* wenc     = (ushort*)alloc(163840); // [10][256][32] bf16
    ushort* wdec     = (ushort*)alloc(221184); // [9][3][8][16][32] bf16
    ushort* apk      = (ushort*)alloc(32768);
    float*  benc     = (float*)alloc(1024);
    float*  bdec     = (float*)alloc(192);
    float*  en       = (float*)alloc(1024);
    float*  wct      = (float*)alloc(32768);   // [30][256] f32 (transposed)
    float*  wcb      = (float*)alloc(32768);
    float*  wcl      = (float*)alloc(32768);
    float*  wcr      = (float*)alloc(32768);
    float*  wcc      = (float*)alloc(12288);   // [12][256] f32

    hipMemsetAsync(loss, 0, sizeof(float), stream);
    hipMemsetAsync(wdec, 0, 221184, stream);

    // weight packing / composition
    k_pack_c3x4<<<9216, 256, 0, stream>>>(er1_w3, er2_w3, dr1_w3, dr2_w3,
                                          wpk_er13, wpk_er23, wpk_dr13, wpk_dr23);
    k_pack_c1x1x4<<<1024, 256, 0, stream>>>(er1_w1, er2_w1, dr1_w1, dr2_w1,
                                            wpk_er11, wpk_er21, wpk_dr11, wpk_dr21);
    k_pack_vq<<<65, 256, 0, stream>>>(codebook, apk, en);
    k_wcomp_enc<<<256, 256, 0, stream>>>(enc_w1, enc_b1, enc_w2, enc_b2, wenc, benc,
                                         wct, wcb, wcl, wcr, wcc);
    k_wcomp_dec<<<256, 256, 0, stream>>>(dt1_w, dt1_b, dt2_w, dt2_b, wdec, bdec);
    k_xpack<<<16384, 256, 0, stream>>>(x, xpk);

    // encoder (composed conv1∘conv2) + exact border fix: x -> X0
    k_enc_comp<<<1024, 128, 0, stream>>>(xpk, wenc, benc, X0);
    k_fix_border<<<32, 256, 0, stream>>>(x, xpk, wct, wcb, wcl, wcr, wcc, X0);
    // fused res blocks (encoder)
    k_resblock<<<512, 256, 0, stream>>>(X0, wpk_er13, wpk_er11, X2);
    k_resblock<<<512, 256, 0, stream>>>(X2, wpk_er23, wpk_er21, X3);
    // VQ: X3 -> X4 (vq, no relu) + loss
    k_vq2<<<2048, 256, 0, stream>>>(X3, apk, en, codebook, X4, loss);
    // fused res blocks (decoder)
    k_resblock<<<512, 256, 0, stream>>>(X4, wpk_dr13, wpk_dr11, X0);
    k_resblock<<<512, 256, 0, stream>>>(X0, wpk_dr23, wpk_dr21, X2);
    // decoder (composed deconv1∘deconv2 + tanh): X2 -> recon
    k_dec_comp<<<512, 128, 0, stream>>>(X2, wdec, bdec, recon);
}

// Round 7
// 544.850 us; speedup vs baseline: 1.4080x; 1.1155x over previous
//
#include <hip/hip_runtime.h>
#include <math.h>

// VQ-VAE forward. R19: k_fix_border parallelized — was 32 blocks (1.3% occ,
// 70 µs, #1 dispatch) doing 64 serial border jobs per thread; now 4096 blocks,
// one border pixel per block (124 jobs/image), one RMW per thread, race-free
// (unique m per job; corner terms folded into the top/bottom jobs with a
// single combined quantization). Everything else byte-identical to R18.

typedef unsigned short ushort;
typedef short bf16x8 __attribute__((ext_vector_type(8)));
typedef float f32x4 __attribute__((ext_vector_type(4)));

__device__ __forceinline__ ushort f2bf(float f) {
    unsigned u = __builtin_bit_cast(unsigned, f);
    unsigned r = (u + 0x7fffu + ((u >> 16) & 1u)) >> 16;
    return (ushort)r;
}
__device__ __forceinline__ float bfl(unsigned u) { return __builtin_bit_cast(float, u << 16); }
__device__ __forceinline__ float bfh(unsigned u) { return __builtin_bit_cast(float, u & 0xffff0000u); }

__device__ __forceinline__ unsigned relu_u(unsigned u) {
    unsigned m = (u >> 15) & 0x00010001u;
    return u & ~((m << 16) - m);
}
__device__ __forceinline__ uint4 relu4(uint4 v) {
    v.x = relu_u(v.x); v.y = relu_u(v.y); v.z = relu_u(v.z); v.w = relu_u(v.w);
    return v;
}

// ======================= weight packing (res blocks, VQ) =======================
__global__ void k_pack_c3x4(const float* __restrict__ w0, const float* __restrict__ w1,
                            const float* __restrict__ w2, const float* __restrict__ w3,
                            ushort* __restrict__ o0, ushort* __restrict__ o1,
                            ushort* __restrict__ o2, ushort* __restrict__ o3) {
    int layer = blockIdx.x / 2304;
    int i = (blockIdx.x - layer * 2304) * 256 + threadIdx.x;     // 589824
    const float* w = layer == 0 ? w0 : layer == 1 ? w1 : layer == 2 ? w2 : w3;
    ushort* o = layer == 0 ? o0 : layer == 1 ? o1 : layer == 2 ? o2 : o3;
    int kk = i & 31, co = (i >> 5) & 255, cb = (i >> 13) & 7, t = i >> 16;
    int ci = cb * 32 + kk, kh = t / 3, kw = t % 3;
    o[i] = f2bf(w[((co * 256 + ci) * 3 + kh) * 3 + kw]);
}

__global__ void k_pack_c1x1x4(const float* __restrict__ w0, const float* __restrict__ w1,
                              const float* __restrict__ w2, const float* __restrict__ w3,
                              ushort* __restrict__ o0, ushort* __restrict__ o1,
                              ushort* __restrict__ o2, ushort* __restrict__ o3) {
    int layer = blockIdx.x >> 8;
    int i = (blockIdx.x & 255) * 256 + threadIdx.x;              // 65536
    const float* w = layer == 0 ? w0 : layer == 1 ? w1 : layer == 2 ? w2 : w3;
    ushort* o = layer == 0 ? o0 : layer == 1 ? o1 : layer == 2 ? o2 : o3;
    int kk = i & 31, co = (i >> 5) & 255, cb = (i >> 13) & 7;
    o[i] = f2bf(w[co * 256 + cb * 32 + kk]);
}

__global__ void k_pack_vq(const float* __restrict__ cb, ushort* __restrict__ apk,
                          float* __restrict__ en) {
    if (blockIdx.x < 64) {
        int i = blockIdx.x * 256 + threadIdx.x;
        int j = i & 7, lane = (i >> 3) & 63, s = (i >> 9) & 1, t = i >> 10;
        int code = t * 16 + (lane & 15);
        int dim = s * 32 + (lane >> 4) * 8 + j;
        apk[i] = f2bf(cb[code * 64 + dim]);
    } else {
        int code = threadIdx.x;
        float s = 0.f;
        for (int d = 0; d < 64; ++d) { float v = cb[code * 64 + d]; s += v * v; }
        en[code] = s;
    }
}

// ======================= encoder weight composition + border-corr weights ======
__global__ __launch_bounds__(256) void k_wcomp_enc(const float* __restrict__ w1,
                                                   const float* __restrict__ b1f,
                                                   const float* __restrict__ w2,
                                                   const float* __restrict__ b2f,
                                                   ushort* __restrict__ wenc,
                                                   float* __restrict__ benc,
                                                   float* __restrict__ wct,
                                                   float* __restrict__ wcb,
                                                   float* __restrict__ wcl,
                                                   float* __restrict__ wcr,
                                                   float* __restrict__ wcc) {
    __shared__ float sw1[12288];   // w1[m][ci][k1h][k1w]
    __shared__ float sw2[4096];    // w2[co][m][k2h][k2w]
    __shared__ float part[2400];
    int co = blockIdx.x, tid = threadIdx.x;
    for (int i = tid; i < 12288; i += 256) sw1[i] = w1[i];
    for (int i = tid; i < 4096; i += 256) sw2[i] = w2[co * 4096 + i];
    __syncthreads();

    {   // bias (exact since b1=0; interior formula)
        float s = 0.f;
#pragma unroll
        for (int t = 0; t < 16; ++t) s += sw2[tid * 16 + t];
        float pb = b1f[tid] * s;
#pragma unroll
        for (int m = 1; m < 64; m <<= 1) pb += __shfl_xor(pb, m);
        if ((tid & 63) == 0) part[tid >> 6] = pb;
    }
    __syncthreads();
    if (tid == 0) benc[co] = b2f[co] + part[0] + part[1] + part[2] + part[3];

    if (tid < 240) {               // t = y*24 + ci*8 + ms
        int y = tid / 24, rem = tid % 24, ci = rem / 8, ms = rem % 8;
        int na = 0, aa[2], h1[2];
#pragma unroll
        for (int a = 0; a < 4; ++a) {
            int k1 = y - 2 * a;
            if ((unsigned)k1 < 4u) { aa[na] = a; h1[na] = k1; ++na; }
        }
        float acc10[10];
#pragma unroll
        for (int xx = 0; xx < 10; ++xx) acc10[xx] = 0.f;
        for (int m = ms * 32; m < ms * 32 + 32; ++m) {
            for (int pa = 0; pa < na; ++pa) {
                float4 a2 = *(const float4*)&sw2[m * 16 + aa[pa] * 4];
                float4 a1 = *(const float4*)&sw1[m * 48 + ci * 16 + h1[pa] * 4];
                acc10[0] += a2.x * a1.x; acc10[1] += a2.x * a1.y; acc10[2] += a2.x * a1.z; acc10[3] += a2.x * a1.w;
                acc10[2] += a2.y * a1.x; acc10[3] += a2.y * a1.y; acc10[4] += a2.y * a1.z; acc10[5] += a2.y * a1.w;
                acc10[4] += a2.z * a1.x; acc10[5] += a2.z * a1.y; acc10[6] += a2.z * a1.z; acc10[7] += a2.z * a1.w;
                acc10[6] += a2.w * a1.x; acc10[7] += a2.w * a1.y; acc10[8] += a2.w * a1.z; acc10[9] += a2.w * a1.w;
            }
        }
#pragma unroll
        for (int xx = 0; xx < 10; ++xx) part[tid * 10 + xx] = acc10[xx];
    }
    __syncthreads();
    for (int w = tid; w < 320; w += 256) {
        if (w < 300) {
            int y = w / 30, r = w % 30, ci = r / 10, xx = r % 10;
            float s = 0.f;
#pragma unroll
            for (int ms = 0; ms < 8; ++ms) s += part[((y * 24 + ci * 8) + ms) * 10 + xx];
            wenc[(y * 256 + co) * 32 + xx * 3 + ci] = f2bf(s);
        } else {
            int j = w - 300;
            int y = j >> 1;
            wenc[(y * 256 + co) * 32 + 30 + (j & 1)] = 0;
        }
    }

    // ---- border-correction weights from LDS ----
    if (tid < 30 || (tid >= 32 && tid < 62)) {
        bool top = tid < 30;
        int t = top ? tid : tid - 32;
        int xx = t / 3, ci = t % 3;
        int k2hf = top ? 0 : 3, k1hf = top ? 3 : 0;
        float s = 0.f;
        for (int m = 0; m < 256; ++m)
            for (int k2w = 0; k2w < 4; ++k2w) {
                int k1w = xx - 2 * k2w;
                if ((unsigned)k1w < 4u)
                    s += sw2[m * 16 + k2hf * 4 + k2w] * sw1[m * 48 + ci * 16 + k1hf * 4 + k1w];
            }
        (top ? wct : wcb)[t * 256 + co] = s;
    } else if ((tid >= 64 && tid < 94) || (tid >= 96 && tid < 126)) {
        bool left = tid < 94;
        int t = left ? tid - 64 : tid - 96;
        int y = t / 3, ci = t % 3;
        int k2wf = left ? 0 : 3, k1wf = left ? 3 : 0;
        float s = 0.f;
        for (int m = 0; m < 256; ++m)
            for (int k2h = 0; k2h < 4; ++k2h) {
                int k1h = y - 2 * k2h;
                if ((unsigned)k1h < 4u)
                    s += sw2[m * 16 + k2h * 4 + k2wf] * sw1[m * 48 + ci * 16 + k1h * 4 + k1wf];
            }
        (left ? wcl : wcr)[t * 256 + co] = s;
    } else if (tid >= 128 && tid < 140) {
        int c = (tid - 128) / 3, ci = (tid - 128) % 3;
        int k2h = (c >> 1) ? 3 : 0, k2w = (c & 1) ? 3 : 0;
        int k1h = 3 - k2h, k1w = 3 - k2w;
        float s = 0.f;
        for (int m = 0; m < 256; ++m)
            s += sw2[m * 16 + k2h * 4 + k2w] * sw1[m * 48 + ci * 16 + k1h * 4 + k1w];
        wcc[(c * 3 + ci) * 256 + co] = s;
    }
}

// ======================= decoder weight composition =======================
__global__ __launch_bounds__(256) void k_wcomp_dec(const float* __restrict__ dt1,
                                                   const float* __restrict__ dt1b,
                                                   const float* __restrict__ dt2,
                                                   const float* __restrict__ dt2b,
                                                   ushort* __restrict__ wdec,
                                                   float* __restrict__ bdec) {
    __shared__ float s1[4096];
    __shared__ float s2[12288];
    __shared__ float part[2400];
    int ci = blockIdx.x, tid = threadIdx.x;
    for (int i = tid; i < 4096; i += 256) s1[i] = dt1[ci * 4096 + i];
    for (int i = tid; i < 12288; i += 256) s2[i] = dt2[i];
    __syncthreads();

    if (ci == 0 && tid < 48) {
        int o = tid >> 4, p = tid & 15, py = p >> 2, px = p & 3;
        int c0 = (py + 1) & 1, d0 = (px + 1) & 1;
        float s = dt2b[o];
        for (int m = 0; m < 256; ++m) {
            float t2 = s2[m * 48 + o * 16 + c0 * 4 + d0] + s2[m * 48 + o * 16 + c0 * 4 + d0 + 2]
                     + s2[m * 48 + o * 16 + (c0 + 2) * 4 + d0] + s2[m * 48 + o * 16 + (c0 + 2) * 4 + d0 + 2];
            s += dt1b[m] * t2;
        }
        bdec[tid] = s;
    }

    if (tid < 240) {
        int y = tid / 24, rem = tid % 24, o = rem / 8, ms = rem % 8;
        int na = 0, aa[2], cc[2];
#pragma unroll
        for (int a = 0; a < 4; ++a) {
            int c = y - 2 * a;
            if ((unsigned)c < 4u) { aa[na] = a; cc[na] = c; ++na; }
        }
        float acc10[10];
#pragma unroll
        for (int xx = 0; xx < 10; ++xx) acc10[xx] = 0.f;
        for (int m = ms * 32; m < ms * 32 + 32; ++m) {
            for (int pa = 0; pa < na; ++pa) {
                float4 d1 = *(const float4*)&s1[m * 16 + aa[pa] * 4];
                float4 d2 = *(const float4*)&s2[m * 48 + o * 16 + cc[pa] * 4];
                acc10[0] += d1.x * d2.x; acc10[1] += d1.x * d2.y; acc10[2] += d1.x * d2.z; acc10[3] += d1.x * d2.w;
                acc10[2] += d1.y * d2.x; acc10[3] += d1.y * d2.y; acc10[4] += d1.y * d2.z; acc10[5] += d1.y * d2.w;
                acc10[4] += d1.z * d2.x; acc10[5] += d1.z * d2.y; acc10[6] += d1.z * d2.z; acc10[7] += d1.z * d2.w;
                acc10[6] += d1.w * d2.x; acc10[7] += d1.w * d2.y; acc10[8] += d1.w * d2.z; acc10[9] += d1.w * d2.w;
            }
        }
#pragma unroll
        for (int xx = 0; xx < 10; ++xx) part[tid * 10 + xx] = acc10[xx];
    }
    __syncthreads();
    for (int w = tid; w < 300; w += 256) {
        int y = w / 30, r = w % 30, o = r / 10, xx = r % 10;
        float s = 0.f;
#pragma unroll
        for (int ms = 0; ms < 8; ++ms) s += part[((y * 24 + o * 8) + ms) * 10 + xx];
        int du = (y < 3) ? 1 : (y < 7) ? 0 : -1;
        int py = y - 3 + 4 * du;
        int dv = (xx < 3) ? 1 : (xx < 7) ? 0 : -1;
        int px = xx - 3 + 4 * dv;
        int t = (du + 1) * 3 + (dv + 1);
        int cb2 = ci >> 5, kk = ci & 31;
        wdec[((((t * 3 + o) * 8 + cb2) * 16 + py * 4 + px) * 32) + kk] = f2bf(s);
    }
}

// ======================= input packing for composed encoder ====================
__global__ void k_xpack(const float* __restrict__ x, ushort* __restrict__ xpk) {
    int i = blockIdx.x * 256 + threadIdx.x;     // 4,194,304
    int k = i & 31, ow = (i >> 5) & 31, r = (i >> 10) & 127, n = i >> 17;
    float v = 0.f;
    if (k < 30) {
        int ci = k % 3, kw = k / 3;
        int col = 4 * ow - 3 + kw;
        if ((unsigned)col < 128u) v = x[((n * 3 + ci) * 128 + r) * 128 + col];
    }
    xpk[i] = f2bf(v);
}

// ======================= composed encoder conv: 3->256 k10 s4, 128->32 =========
__global__ __launch_bounds__(128) void k_enc_comp(const ushort* __restrict__ xpk,
                                                  const ushort* __restrict__ wenc,
                                                  const float* __restrict__ benc,
                                                  ushort* __restrict__ obf) {
    int tid = threadIdx.x, lane = tid & 63, wv = tid >> 6;
    int q = lane >> 4, l15 = lane & 15;
    int b = blockIdx.x;
    int mblk = b & 7, coslab = (b >> 3) & 3, n = b >> 5;
    int R0 = mblk * 4 + wv * 2;
    int aoff = (coslab * 64 + l15) * 32 + q * 8;

    f32x4 acc[4][4];
#pragma unroll
    for (int at = 0; at < 4; ++at)
#pragma unroll
        for (int bt = 0; bt < 4; ++bt) acc[at][bt] = 0.f;

    for (int t = 0; t < 10; ++t) {
        bf16x8 af[4];
#pragma unroll
        for (int at = 0; at < 4; ++at)
            af[at] = *(const bf16x8*)(wenc + t * 8192 + aoff + at * 512);
#pragma unroll
        for (int bt2 = 0; bt2 < 2; ++bt2) {
            int irow = 4 * (R0 + bt2) + t - 3;
            if ((unsigned)irow >= 128u) continue;      // x zero padding -> skip
            bf16x8 bf[2];
#pragma unroll
            for (int hb = 0; hb < 2; ++hb) {
                int ow = hb * 16 + l15;
                bf[hb] = *(const bf16x8*)(xpk + (((long)n * 128 + irow) * 32 + ow) * 32 + q * 8);
            }
#pragma unroll
            for (int at = 0; at < 4; ++at)
#pragma unroll
                for (int hb = 0; hb < 2; ++hb)
                    acc[at][bt2 * 2 + hb] = __builtin_amdgcn_mfma_f32_16x16x32_bf16(
                        af[at], bf[hb], acc[at][bt2 * 2 + hb], 0, 0, 0);
        }
    }

    int co_base = coslab * 64;
#pragma unroll
    for (int at = 0; at < 4; ++at) {
        int co_t = co_base + at * 16 + q * 4;
        float4 b4 = *(const float4*)(benc + co_t);
        float bv[4] = {b4.x, b4.y, b4.z, b4.w};
#pragma unroll
        for (int bt = 0; bt < 4; ++bt) {
            int m = R0 * 32 + bt * 16 + l15;
            long oaddr = ((long)n * 1024 + m) * 256 + co_t;
            float v[4];
#pragma unroll
            for (int r = 0; r < 4; ++r) v[r] = acc[at][bt][r] + bv[r];
            uint2 pk;
            pk.x = (unsigned)f2bf(v[0]) | ((unsigned)f2bf(v[1]) << 16);
            pk.y = (unsigned)f2bf(v[2]) | ((unsigned)f2bf(v[3]) << 16);
            *(uint2*)(obf + oaddr) = pk;
        }
    }
}

// ======================= border fix (parallel): one border pixel per block =====
// 124 jobs/image: job<32 top (m=q), <64 bottom (m=992+q), <94 left p=1..30
// (m=32p), <124 right p=1..30 (m=32p+31). Corner terms folded into top/bottom
// jobs; each output m is touched by exactly ONE block -> race-free. Single
// combined quantization per pixel (tighter than the old 3-step RMW chain).
__global__ __launch_bounds__(256) void k_fix_border(const float* __restrict__ x,
                                                    const ushort* __restrict__ xpk,
                                                    const float* __restrict__ wct,
                                                    const float* __restrict__ wcb,
                                                    const float* __restrict__ wcl,
                                                    const float* __restrict__ wcr,
                                                    const float* __restrict__ wcc,
                                                    ushort* __restrict__ X0) {
    int b = blockIdx.x;
    int n = b >> 7, job = b & 127;
    if (job >= 124) return;
    int co = threadIdx.x;

    auto dot_tb = [&](const float* __restrict__ w, int row, int qq) -> float {
        const ushort* xr = xpk + (((long)n * 128 + row) * 32 + qq) * 32;
        float s = 0.f;
        for (int k = 0; k < 30; ++k) s += w[k * 256 + co] * bfl((unsigned)xr[k]);
        return s;
    };
    auto dot_lr = [&](const float* __restrict__ w, int p, int colofs) -> float {
        float s = 0.f;
        for (int y = 0; y < 10; ++y) {
            int row = 4 * p - 3 + y;
            if ((unsigned)row >= 128u) continue;
            for (int ci = 0; ci < 3; ++ci)
                s += w[(y * 3 + ci) * 256 + co] * x[((long)(n * 3 + ci) * 128 + row) * 128 + colofs];
        }
        return s;
    };
    auto corner = [&](int c, int row, int colofs) -> float {
        float s = 0.f;
        for (int ci = 0; ci < 3; ++ci)
            s += wcc[(c * 3 + ci) * 256 + co] * x[((long)(n * 3 + ci) * 128 + row) * 128 + colofs];
        return s;
    };

    int m;
    float corr;
    if (job < 32) {                       // top row p=0
        int qq = job;
        m = qq;
        corr = dot_tb(wct, 0, qq);
        if (qq == 0)  corr += dot_lr(wcl, 0, 0)   - corner(0, 0, 0);
        if (qq == 31) corr += dot_lr(wcr, 0, 127) - corner(1, 0, 127);
    } else if (job < 64) {                // bottom row p=31
        int qq = job - 32;
        m = 992 + qq;
        corr = dot_tb(wcb, 127, qq);
        if (qq == 0)  corr += dot_lr(wcl, 31, 0)   - corner(2, 127, 0);
        if (qq == 31) corr += dot_lr(wcr, 31, 127) - corner(3, 127, 127);
    } else if (job < 94) {                // left col q=0, p=1..30
        int p = job - 63;
        m = 32 * p;
        corr = dot_lr(wcl, p, 0);
    } else {                              // right col q=31, p=1..30
        int p = job - 93;
        m = 32 * p + 31;
        corr = dot_lr(wcr, p, 127);
    }

    ushort* ptr = X0 + ((long)n * 1024 + m) * 256 + co;
    float v = bfl((unsigned)(*ptr));
    *ptr = f2bf(v - corr);
}

// ======================= fused res block (R15-verified tiling) =================
__global__ __launch_bounds__(256, 2) void k_resblock(const ushort* __restrict__ xin,
                                                     const ushort* __restrict__ w3pk,
                                                     const ushort* __restrict__ w1pk,
                                                     ushort* __restrict__ obf) {
    constexpr int BUFU = 4 * 4 * 34 * 8;             // 4352 ushorts = 8704 B
    __shared__ __align__(16) ushort sX[2 * BUFU];    // 17408 B staging
    __shared__ __align__(16) ushort sEx[64 * 256];   // 32768 B exchange

    int tid = threadIdx.x, lane = tid & 63, wv = tid >> 6;
    int q = lane >> 4, l15 = lane & 15;
    int b = blockIdx.x;                              // 32n * 16 rowpairs
    int rp = b & 15, n = b >> 4;
    int R0 = rp * 2;

    if (tid < 64) {
        int bufi = tid >> 5, rq = (tid >> 1) & 15, cc = (tid & 1) ? 33 : 0;
        uint4 z; z.x = z.y = z.z = z.w = 0;
        *(uint4*)&sX[bufi * BUFU + (rq * 34 + cc) * 8] = z;
    }

    int brr[4], bcol[4];
#pragma unroll
    for (int bt = 0; bt < 4; ++bt) {
        int p = bt * 16 + l15;
        brr[bt] = p >> 5; bcol[bt] = (p & 31) + 1;
    }

    int scol = lane >> 1, j0 = (lane & 1) * 2;
    int aoff = (wv * 64 + l15) * 32 + q * 8;

    f32x4 acc[4][4];
#pragma unroll
    for (int at = 0; at < 4; ++at)
#pragma unroll
        for (int bt = 0; bt < 4; ++bt) acc[at][bt] = 0.f;

    int hh = R0 - 1 + wv;
    bool hvalid = (unsigned)hh < 32u;
    uint4 sreg[2];
    auto stage_load = [&](int cb2) {
        long off = (((long)n * 32 + hh) * 32 + scol) * 256 + cb2 * 32 + j0 * 8;
#pragma unroll
        for (int k = 0; k < 2; ++k) {
            uint4 v;
            if (hvalid) v = relu4(*(const uint4*)(xin + off + k * 8));
            else { v.x = 0; v.y = 0; v.z = 0; v.w = 0; }
            sreg[k] = v;
        }
    };
    auto write_stage = [&](int pbuf) {
        ushort* bufp = sX + pbuf * BUFU;
#pragma unroll
        for (int k = 0; k < 2; ++k)
            *(uint4*)&bufp[((wv * 4 + j0 + k) * 34 + scol + 1) * 8] = sreg[k];
    };

    stage_load(0);
    write_stage(0);
    __syncthreads();

    for (int cb = 0; cb < 8; ++cb) {
        ushort* bufp = sX + (cb & 1) * BUFU;
        if (cb + 1 < 8) stage_load(cb + 1);
        const ushort* wb = w3pk + (long)cb * 8192 + aoff;

        bf16x8 afc[4];
#pragma unroll
        for (int at = 0; at < 4; ++at) afc[at] = *(const bf16x8*)(wb + at * 512);
#pragma unroll
        for (int t = 0; t < 9; ++t) {
            bf16x8 afn[4];
            if (t < 8) {
#pragma unroll
                for (int at = 0; at < 4; ++at)
                    afn[at] = *(const bf16x8*)(wb + (long)(t + 1) * 65536 + at * 512);
            }
            int taprow = t / 3, dx = t % 3 - 1;
            bf16x8 bfr[4];
#pragma unroll
            for (int bt = 0; bt < 4; ++bt)
                bfr[bt] = *(const bf16x8*)&bufp[(((brr[bt] + taprow) * 4 + q) * 34 + bcol[bt] + dx) * 8];
#pragma unroll
            for (int at = 0; at < 4; ++at)
#pragma unroll
                for (int bt = 0; bt < 4; ++bt)
                    acc[at][bt] = __builtin_amdgcn_mfma_f32_16x16x32_bf16(afc[at], bfr[bt],
                                                                          acc[at][bt], 0, 0, 0);
            if (t < 8) {
#pragma unroll
                for (int at = 0; at < 4; ++at) afc[at] = afn[at];
            }
        }

        if (cb + 1 < 8) {
            write_stage((cb + 1) & 1);
            __syncthreads();
        }
    }

#pragma unroll
    for (int at = 0; at < 4; ++at) {
        int co_t = wv * 64 + at * 16 + q * 4;
#pragma unroll
        for (int bt = 0; bt < 4; ++bt) {
            int px = bt * 16 + l15;
            uint2 pk;
            pk.x = (unsigned)f2bf(fmaxf(acc[at][bt][0], 0.f))
                 | ((unsigned)f2bf(fmaxf(acc[at][bt][1], 0.f)) << 16);
            pk.y = (unsigned)f2bf(fmaxf(acc[at][bt][2], 0.f))
                 | ((unsigned)f2bf(fmaxf(acc[at][bt][3], 0.f)) << 16);
            *(uint2*)&sEx[px * 256 + (co_t ^ ((px & 7) << 3))] = pk;
        }
    }
    __syncthreads();

    f32x4 acc2[4][4];
#pragma unroll
    for (int at = 0; at < 4; ++at)
#pragma unroll
        for (int bt = 0; bt < 4; ++bt) acc2[at][bt] = 0.f;

    for (int cb = 0; cb < 8; ++cb) {
        const ushort* wb1 = w1pk + (long)cb * 8192 + aoff;
        bf16x8 af1[4];
#pragma unroll
        for (int at = 0; at < 4; ++at) af1[at] = *(const bf16x8*)(wb1 + at * 512);
        bf16x8 bf1[4];
#pragma unroll
        for (int bt = 0; bt < 4; ++bt) {
            int px = bt * 16 + l15;
            bf1[bt] = *(const bf16x8*)&sEx[px * 256 + ((cb * 32 + q * 8) ^ ((px & 7) << 3))];
        }
#pragma unroll
        for (int at = 0; at < 4; ++at)
#pragma unroll
            for (int bt = 0; bt < 4; ++bt)
                acc2[at][bt] = __builtin_amdgcn_mfma_f32_16x16x32_bf16(af1[at], bf1[bt],
                                                                      acc2[at][bt], 0, 0, 0);
    }

#pragma unroll
    for (int at = 0; at < 4; ++at) {
        int co_t = wv * 64 + at * 16 + q * 4;
#pragma unroll
        for (int bt = 0; bt < 4; ++bt) {
            int m = R0 * 32 + bt * 16 + l15;
            long oaddr = ((long)n * 1024 + m) * 256 + co_t;
            uint2 rr = *(const uint2*)(xin + oaddr);
            float v[4];
            v[0] = acc2[at][bt][0] + bfl(rr.x);
            v[1] = acc2[at][bt][1] + bfh(rr.x);
            v[2] = acc2[at][bt][2] + bfl(rr.y);
            v[3] = acc2[at][bt][3] + bfh(rr.y);
            uint2 pk;
            pk.x = (unsigned)f2bf(v[0]) | ((unsigned)f2bf(v[1]) << 16);
            pk.y = (unsigned)f2bf(v[2]) | ((unsigned)f2bf(v[3]) << 16);
            *(uint2*)(obf + oaddr) = pk;
        }
    }
}

// ======================= VQ via MFMA (bf16 out) =======================
__global__ __launch_bounds__(256) void k_vq2(const ushort* __restrict__ zb,
                                             const ushort* __restrict__ apk,
                                             const float* __restrict__ en,
                                             const float* __restrict__ cbf,
                                             ushort* __restrict__ vqb,
                                             float* __restrict__ loss) {
    __shared__ int sIdx[64];
    __shared__ float sLoss[64];
    int tid = threadIdx.x, lane = tid & 63, wv = tid >> 6;
    int q = lane >> 4, l15 = lane & 15;
    int r0 = blockIdx.x * 64;
    int R = r0 + wv * 16;

    const ushort* zp = zb + ((long)(R + l15)) * 64 + q * 8;
    bf16x8 b0 = *(const bf16x8*)zp;
    bf16x8 b1 = *(const bf16x8*)(zp + 32);

    float z2 = 0.f;
    {
        const unsigned* u0 = (const unsigned*)&b0;
        const unsigned* u1 = (const unsigned*)&b1;
#pragma unroll
        for (int i = 0; i < 4; ++i) {
            float a = bfl(u0[i]), bb = bfh(u0[i]);
            float c = bfl(u1[i]), d = bfh(u1[i]);
            z2 += a * a + bb * bb + c * c + d * d;
        }
    }

    float best = 3.4e38f;
    int bidx = 0;
#pragma unroll
    for (int t = 0; t < 16; ++t) {
        bf16x8 a0 = *(const bf16x8*)(apk + ((t * 2 + 0) * 64 + lane) * 8);
        bf16x8 a1 = *(const bf16x8*)(apk + ((t * 2 + 1) * 64 + lane) * 8);
        f32x4 acc = {0.f, 0.f, 0.f, 0.f};
        acc = __builtin_amdgcn_mfma_f32_16x16x32_bf16(a0, b0, acc, 0, 0, 0);
        acc = __builtin_amdgcn_mfma_f32_16x16x32_bf16(a1, b1, acc, 0, 0, 0);
        float4 e4 = *(const float4*)(en + t * 16 + q * 4);
        float sc[4] = {e4.x - 2.f * acc[0], e4.y - 2.f * acc[1],
                       e4.z - 2.f * acc[2], e4.w - 2.f * acc[3]};
#pragma unroll
        for (int r = 0; r < 4; ++r) {
            int code = t * 16 + q * 4 + r;
            if (sc[r] < best) { best = sc[r]; bidx = code; }
        }
    }
#pragma unroll
    for (int m = 16; m <= 32; m <<= 1) {
        float ob = __shfl_xor(best, m);
        int oi = __shfl_xor(bidx, m);
        if (ob < best || (ob == best && oi < bidx)) { best = ob; bidx = oi; }
        z2 += __shfl_xor(z2, m);
    }
    if (q == 0) {
        sIdx[wv * 16 + l15] = bidx;
        sLoss[wv * 16 + l15] = best + z2;
    }
    __syncthreads();

    if (wv == 0) {
        float l = sLoss[lane];
#pragma unroll
        for (int m = 1; m < 64; m <<= 1) l += __shfl_xor(l, m);
        if (lane == 0) atomicAdd(loss, l * (1.25f / 8388608.f));
    }

    unsigned* vb = (unsigned*)(vqb + (long)r0 * 64);
#pragma unroll
    for (int k = 0; k < 8; ++k) {
        int i = k * 256 + tid;
        int rl = i >> 5, jp = i & 31;
        int idx = sIdx[rl];
        float v0 = cbf[idx * 64 + 2 * jp];
        float v1 = cbf[idx * 64 + 2 * jp + 1];
        vb[i] = (unsigned)f2bf(v0) | ((unsigned)f2bf(v1) << 16);
    }
}

// ======================= composed decoder deconv: 256->3 k10 s4, 32->128 ========
__global__ __launch_bounds__(128, 2) void k_dec_comp(const ushort* __restrict__ xin,
                                                     const ushort* __restrict__ wdec,
                                                     const float* __restrict__ bdec,
                                                     float* __restrict__ out) {
    constexpr int BUFU = 3 * 4 * 34 * 8;             // 3264 ushorts
    constexpr int WLDS = 2 * BUFU;
    __shared__ __align__(16) ushort sX[2 * WLDS];    // 26112 B

    int tid = threadIdx.x, lane = tid & 63, wv = tid >> 6;
    int q = lane >> 4, l15 = lane & 15;
    int b = blockIdx.x;                              // 32n * 16rp
    int rp = b & 15, n = b >> 4;
    int U = rp * 2 + wv;
    ushort* sW = sX + wv * WLDS;

    if (lane < 48) {
        int cc = (lane & 1) ? 33 : 0;
        int sq = lane >> 1;
        uint4 z; z.x = z.y = z.z = z.w = 0;
        *(uint4*)&sW[(sq * 34 + cc) * 8] = z;
    }
    int scol = lane >> 1, j0 = (lane & 1) * 2;

    f32x4 acc[3][2];
#pragma unroll
    for (int o = 0; o < 3; ++o)
#pragma unroll
        for (int bt = 0; bt < 2; ++bt) acc[o][bt] = 0.f;

    uint4 sreg[3][2];
    auto stage_load = [&](int cb2) {
#pragma unroll
        for (int r = 0; r < 3; ++r) {
            int hh = U - 1 + r;
            bool valid = (unsigned)hh < 32u;
            long off = (((long)n * 32 + hh) * 32 + scol) * 256 + cb2 * 32 + j0 * 8;
#pragma unroll
            for (int k = 0; k < 2; ++k) {
                uint4 v;
                if (valid) v = *(const uint4*)(xin + off + k * 8);
                else { v.x = 0; v.y = 0; v.z = 0; v.w = 0; }
                sreg[r][k] = v;
            }
        }
    };
    auto write_stage = [&](int pbuf) {
        ushort* bufp = sW + pbuf * BUFU;
#pragma unroll
        for (int r = 0; r < 3; ++r)
#pragma unroll
            for (int k = 0; k < 2; ++k)
                *(uint4*)&bufp[((r * 4 + j0 + k) * 34 + scol + 1) * 8] = sreg[r][k];
    };

    stage_load(0);
    write_stage(0);

    for (int cb = 0; cb < 8; ++cb) {
        ushort* bufp = sW + (cb & 1) * BUFU;
        if (cb + 1 < 8) stage_load(cb + 1);
        const ushort* wb = wdec + (long)cb * 512 + l15 * 32 + q * 8;
#pragma unroll
        for (int t = 0; t < 9; ++t) {
            int du = t / 3 - 1, dv = t % 3 - 1;
            bf16x8 bfr[2];
#pragma unroll
            for (int bt = 0; bt < 2; ++bt)
                bfr[bt] = *(const bf16x8*)&bufp[(((du + 1) * 4 + q) * 34 + bt * 16 + l15 + 1 + dv) * 8];
#pragma unroll
            for (int o = 0; o < 3; ++o) {
                bf16x8 af = *(const bf16x8*)(wb + (long)(t * 3 + o) * 4096);
#pragma unroll
                for (int bt = 0; bt < 2; ++bt)
                    acc[o][bt] = __builtin_amdgcn_mfma_f32_16x16x32_bf16(af, bfr[bt], acc[o][bt], 0, 0, 0);
            }
        }
        if (cb + 1 < 8) write_stage((cb + 1) & 1);
    }

#pragma unroll
    for (int o = 0; o < 3; ++o) {
#pragma unroll
        for (int bt = 0; bt < 2; ++bt) {
            int V = bt * 16 + l15;
#pragma unroll
            for (int r = 0; r < 4; ++r) {
                int p = q * 4 + r, py = p >> 2, px = p & 3;
                out[(((long)n * 3 + o) * 128 + 4 * U + py) * 128 + 4 * V + px] =
                    tanhf(acc[o][bt][r] + bdec[o * 16 + p]);
            }
        }
    }
}

// ======================= launcher =======================
extern "C" void kernel_launch(void* const* d_in, const int* in_sizes, int n_in,
                              void* d_out, int out_size, void* d_ws, size_t ws_size,
                              hipStream_t stream) {
    (void)in_sizes; (void)n_in; (void)out_size; (void)ws_size;
    const float* x        = (const float*)d_in[0];
    const float* enc_w1   = (const float*)d_in[1];
    const float* enc_b1   = (const float*)d_in[2];
    const float* enc_w2   = (const float*)d_in[3];
    const float* enc_b2   = (const float*)d_in[4];
    const float* er1_w3   = (const float*)d_in[5];
    const float* er1_w1   = (const float*)d_in[6];
    const float* er2_w3   = (const float*)d_in[7];
    const float* er2_w1   = (const float*)d_in[8];
    const float* codebook = (const float*)d_in[9];
    const float* dr1_w3   = (const float*)d_in[10];
    const float* dr1_w1   = (const float*)d_in[11];
    const float* dr2_w3   = (const float*)d_in[12];
    const float* dr2_w1   = (const float*)d_in[13];
    const float* dt1_w    = (const float*)d_in[14];
    const float* dt1_b    = (const float*)d_in[15];
    const float* dt2_w    = (const float*)d_in[16];
    const float* dt2_b    = (const float*)d_in[17];

    float* recon = (float*)d_out;
    float* loss  = recon + 1572864;

    char* ws = (char*)d_ws;
    size_t off = 0;
    auto alloc = [&](size_t bytes) { char* p = ws + off; off += (bytes + 255) & ~(size_t)255; return p; };
    ushort* X0   = (ushort*)alloc(16777216);   // bf16 NHWC 32x32 tensors
    ushort* X2   = (ushort*)alloc(16777216);
    ushort* X3   = (ushort*)alloc(16777216);
    ushort* X4   = (ushort*)alloc(16777216);
    ushort* xpk  = (ushort*)alloc(8388608);    // [32][128][32][32] bf16
    ushort* wpk_er13 = (ushort*)alloc(1179648);
    ushort* wpk_er23 = (ushort*)alloc(1179648);
    ushort* wpk_dr13 = (ushort*)alloc(1179648);
    ushort* wpk_dr23 = (ushort*)alloc(1179648);
    ushort* wpk_er11 = (ushort*)alloc(131072);
    ushort* wpk_er21 = (ushort*)alloc(131072);
    ushort* wpk_dr11 = (ushort*)alloc(131072);
    ushort* wpk_dr21 = (ushort*)alloc(131072);
    ushort* wenc     = (ushort*)alloc(163840); // [10][256][32] bf16
    ushort* wdec     = (ushort*)alloc(221184); // [9][3][8][16][32] bf16
    ushort* apk      = (ushort*)alloc(32768);
    float*  benc     = (float*)alloc(1024);
    float*  bdec     = (float*)alloc(192);
    float*  en       = (float*)alloc(1024);
    float*  wct      = (float*)alloc(32768);   // [30][256] f32 (transposed)
    float*  wcb      = (float*)alloc(32768);
    float*  wcl      = (float*)alloc(32768);
    float*  wcr      = (float*)alloc(32768);
    float*  wcc      = (float*)alloc(12288);   // [12][256] f32

    hipMemsetAsync(loss, 0, sizeof(float), stream);
    hipMemsetAsync(wdec, 0, 221184, stream);

    // weight packing / composition
    k_pack_c3x4<<<9216, 256, 0, stream>>>(er1_w3, er2_w3, dr1_w3, dr2_w3,
                                          wpk_er13, wpk_er23, wpk_dr13, wpk_dr23);
    k_pack_c1x1x4<<<1024, 256, 0, stream>>>(er1_w1, er2_w1, dr1_w1, dr2_w1,
                                            wpk_er11, wpk_er21, wpk_dr11, wpk_dr21);
    k_pack_vq<<<65, 256, 0, stream>>>(codebook, apk, en);
    k_wcomp_enc<<<256, 256, 0, stream>>>(enc_w1, enc_b1, enc_w2, enc_b2, wenc, benc,
                                         wct, wcb, wcl, wcr, wcc);
    k_wcomp_dec<<<256, 256, 0, stream>>>(dt1_w, dt1_b, dt2_w, dt2_b, wdec, bdec);
    k_xpack<<<16384, 256, 0, stream>>>(x, xpk);

    // encoder (composed conv1∘conv2) + exact border fix: x -> X0
    k_enc_comp<<<1024, 128, 0, stream>>>(xpk, wenc, benc, X0);
    k_fix_border<<<4096, 256, 0, stream>>>(x, xpk, wct, wcb, wcl, wcr, wcc, X0);
    // fused res blocks (encoder)
    k_resblock<<<512, 256, 0, stream>>>(X0, wpk_er13, wpk_er11, X2);
    k_resblock<<<512, 256, 0, stream>>>(X2, wpk_er23, wpk_er21, X3);
    // VQ: X3 -> X4 (vq, no relu) + loss
    k_vq2<<<2048, 256, 0, stream>>>(X3, apk, en, codebook, X4, loss);
    // fused res blocks (decoder)
    k_resblock<<<512, 256, 0, stream>>>(X4, wpk_dr13, wpk_dr11, X0);
    k_resblock<<<512, 256, 0, stream>>>(X0, wpk_dr23, wpk_dr21, X2);
    // decoder (composed deconv1∘deconv2 + tanh): X2 -> recon
    k_dec_comp<<<512, 128, 0, stream>>>(X2, wdec, bdec, recon);
}